// Round 1
// baseline (8477.234 us; speedup 1.0000x reference)
//
#include <hip/hip_runtime.h>
#include <hip/hip_bf16.h>
#include <math.h>

#define N_NODES 50000
#define NEDGE 800000
#define NET 3
#define LAYERS 3
#define HEADS 4
#define DHEAD 64
#define NH 256
#define NC 16
#define NEG_SLOPE 0.2f

// ---------------- GEMM: C[M x 256] = A[M x 256] @ B[256 x 256], fp32 ----------------
__global__ __launch_bounds__(256) void gemm_f32(const float* __restrict__ A,
                                                const float* __restrict__ B,
                                                float* __restrict__ C, int M) {
  __shared__ float As[16][65];
  __shared__ float Bs[16][65];
  const int K = 256;
  int bm = blockIdx.x * 64;
  int bn = blockIdx.y * 64;
  int tid = threadIdx.x;
  int tx = tid & 15, ty = tid >> 4;
  float acc[4][4];
#pragma unroll
  for (int i = 0; i < 4; i++)
#pragma unroll
    for (int j = 0; j < 4; j++) acc[i][j] = 0.f;

  for (int k0 = 0; k0 < K; k0 += 16) {
#pragma unroll
    for (int i = 0; i < 4; i++) {
      int idx = tid + i * 256;          // 0..1023 : A tile 64 rows x 16 k
      int r = idx >> 4, c = idx & 15;
      int row = bm + r;
      As[c][r] = (row < M) ? A[(size_t)row * K + k0 + c] : 0.f;
    }
#pragma unroll
    for (int i = 0; i < 4; i++) {
      int idx = tid + i * 256;          // B tile 16 k x 64 cols
      int r = idx >> 6, c = idx & 63;
      Bs[r][c] = B[(size_t)(k0 + r) * 256 + bn + c];
    }
    __syncthreads();
#pragma unroll
    for (int kk = 0; kk < 16; kk++) {
      float a[4], b[4];
#pragma unroll
      for (int i = 0; i < 4; i++) a[i] = As[kk][ty * 4 + i];
#pragma unroll
      for (int j = 0; j < 4; j++) b[j] = Bs[kk][tx * 4 + j];
#pragma unroll
      for (int i = 0; i < 4; i++)
#pragma unroll
        for (int j = 0; j < 4; j++) acc[i][j] = fmaf(a[i], b[j], acc[i][j]);
    }
    __syncthreads();
  }
#pragma unroll
  for (int i = 0; i < 4; i++) {
    int row = bm + ty * 4 + i;
    if (row < M) {
#pragma unroll
      for (int j = 0; j < 4; j++) C[(size_t)row * 256 + bn + tx * 4 + j] = acc[i][j];
    }
  }
}

// ---------------- el/er: per-node per-head dot of z with attn vectors ----------------
__global__ __launch_bounds__(256) void scores_kernel(const float* __restrict__ z,
                                                     const float* __restrict__ al,
                                                     const float* __restrict__ ar,
                                                     float* __restrict__ el,
                                                     float* __restrict__ er) {
  int n = blockIdx.x;
  int j = threadIdx.x;                  // 0..255 ; head = j>>6
  float zv = z[(size_t)n * NH + j];
  float l = zv * al[j];
  float r = zv * ar[j];
#pragma unroll
  for (int off = 32; off > 0; off >>= 1) {
    l += __shfl_down(l, off, 64);
    r += __shfl_down(r, off, 64);
  }
  if ((j & 63) == 0) {
    int h = j >> 6;
    el[n * HEADS + h] = l;
    er[n * HEADS + h] = r;
  }
}

// ---------------- monotone float<->uint map for atomic max ----------------
__device__ inline unsigned fmap(float f) {
  unsigned u = __float_as_uint(f);
  return (u & 0x80000000u) ? ~u : (u | 0x80000000u);
}
__device__ inline float funmap(unsigned u) {
  return (u & 0x80000000u) ? __uint_as_float(u ^ 0x80000000u) : __uint_as_float(~u);
}

__device__ inline float leaky(float v) { return v > 0.f ? v : NEG_SLOPE * v; }

__global__ void edge_max_kernel(const int* __restrict__ src, const int* __restrict__ dst,
                                const float* __restrict__ el, const float* __restrict__ er,
                                unsigned* __restrict__ mmax) {
  int i = blockIdx.x * blockDim.x + threadIdx.x;
  if (i >= NEDGE * HEADS) return;
  int e = i >> 2, h = i & 3;
  int s = src[e], d = dst[e];
  float v = leaky(el[s * HEADS + h] + er[d * HEADS + h]);
  atomicMax(&mmax[d * HEADS + h], fmap(v));
}

__global__ void edge_den_kernel(const int* __restrict__ src, const int* __restrict__ dst,
                                const float* __restrict__ el, const float* __restrict__ er,
                                const unsigned* __restrict__ mmax, float* __restrict__ denom) {
  int i = blockIdx.x * blockDim.x + threadIdx.x;
  if (i >= NEDGE * HEADS) return;
  int e = i >> 2, h = i & 3;
  int s = src[e], d = dst[e];
  float v = leaky(el[s * HEADS + h] + er[d * HEADS + h]);
  float m = funmap(mmax[d * HEADS + h]);
  atomicAdd(&denom[d * HEADS + h], expf(v - m));
}

// one block (256 thr) per edge: thread j handles feature j, head j>>6
__global__ __launch_bounds__(256) void edge_agg_kernel(const int* __restrict__ src,
                                                       const int* __restrict__ dst,
                                                       const float* __restrict__ el,
                                                       const float* __restrict__ er,
                                                       const unsigned* __restrict__ mmax,
                                                       const float* __restrict__ denom,
                                                       const float* __restrict__ z,
                                                       float* __restrict__ acc) {
  int e = blockIdx.x;
  int j = threadIdx.x;
  int h = j >> 6;
  int s = src[e], d = dst[e];
  float v = leaky(el[s * HEADS + h] + er[d * HEADS + h]);
  float m = funmap(mmax[d * HEADS + h]);
  float alpha = expf(v - m) / denom[d * HEADS + h];
  atomicAdd(&acc[(size_t)d * NH + j], alpha * z[(size_t)s * NH + j]);
}

__global__ void bias_relu_kernel(float* __restrict__ h, const float* __restrict__ b0,
                                 const float* __restrict__ b1, const float* __restrict__ b2,
                                 int do_relu) {
  int i = blockIdx.x * blockDim.x + threadIdx.x;
  if (i >= N_NODES * NH) return;
  int j = i & 255;
  float v = h[i] + b0[j] + b1[j] + b2[j];
  h[i] = (do_relu && v < 0.f) ? 0.f : v;
}

// out[n][c] = sum_j h[n][j] * w[j][c] + b[c]
__global__ __launch_bounds__(256) void linear_kernel(const float* __restrict__ h,
                                                     const float* __restrict__ w,
                                                     const float* __restrict__ b,
                                                     float* __restrict__ out) {
  __shared__ float part[16][17];
  int n = blockIdx.x;
  int t = threadIdx.x;
  int c = t & 15, p = t >> 4;
  float sum = 0.f;
#pragma unroll
  for (int q = 0; q < 16; q++) {
    int j = p * 16 + q;
    sum = fmaf(h[(size_t)n * NH + j], w[j * NC + c], sum);
  }
  part[p][c] = sum;
  __syncthreads();
  if (t < 16) {
    float s = 0.f;
#pragma unroll
    for (int p2 = 0; p2 < 16; p2++) s += part[p2][t];
    out[n * NC + t] = s + b[t];
  }
}

extern "C" void kernel_launch(void* const* d_in, const int* in_sizes, int n_in,
                              void* d_out, int out_size, void* d_ws, size_t ws_size,
                              hipStream_t stream) {
  const float* x      = (const float*)d_in[0];
  const int*   src    = (const int*)d_in[1];
  const int*   dst    = (const int*)d_in[2];
  const float* W      = (const float*)d_in[3];
  const float* attn_l = (const float*)d_in[4];
  const float* attn_r = (const float*)d_in[5];
  const float* bias   = (const float*)d_in[6];
  const float* lin_w  = (const float*)d_in[7];
  const float* lin_b  = (const float*)d_in[8];
  float* out = (float*)d_out;

  char* ws = (char*)d_ws;
  size_t off = 0;
  float* h0 = (float*)(ws + off); off += (size_t)N_NODES * NH * 4;
  float* h1 = (float*)(ws + off); off += (size_t)N_NODES * NH * 4;
  float* z  = (float*)(ws + off); off += (size_t)N_NODES * NH * 4;
  float* el = (float*)(ws + off); off += (size_t)N_NODES * HEADS * 4;
  float* er = (float*)(ws + off); off += (size_t)N_NODES * HEADS * 4;
  unsigned* mmax = (unsigned*)(ws + off); off += (size_t)N_NODES * HEADS * 4;
  float* denom   = (float*)(ws + off); off += (size_t)N_NODES * HEADS * 4;

  const float* h_cur = x;
  float* h_next = h0;

  for (int l = 0; l < LAYERS; l++) {
    hipMemsetAsync(h_next, 0, (size_t)N_NODES * NH * 4, stream);
    for (int t = 0; t < NET; t++) {
      const float* Wlt = W      + (size_t)(l * NET + t) * NH * NH;
      const float* al  = attn_l + (size_t)(l * NET + t) * HEADS * DHEAD;
      const float* ar  = attn_r + (size_t)(l * NET + t) * HEADS * DHEAD;
      const int* s_t = src + (size_t)t * NEDGE;
      const int* d_t = dst + (size_t)t * NEDGE;

      dim3 gg((N_NODES + 63) / 64, NH / 64);
      gemm_f32<<<gg, 256, 0, stream>>>(h_cur, Wlt, z, N_NODES);
      scores_kernel<<<N_NODES, 256, 0, stream>>>(z, al, ar, el, er);

      hipMemsetAsync(mmax, 0, (size_t)N_NODES * HEADS * 4, stream);
      hipMemsetAsync(denom, 0, (size_t)N_NODES * HEADS * 4, stream);

      int threads = 256;
      int blocks = (NEDGE * HEADS + threads - 1) / threads;
      edge_max_kernel<<<blocks, threads, 0, stream>>>(s_t, d_t, el, er, mmax);
      edge_den_kernel<<<blocks, threads, 0, stream>>>(s_t, d_t, el, er, mmax, denom);
      edge_agg_kernel<<<NEDGE, 256, 0, stream>>>(s_t, d_t, el, er, mmax, denom, z, h_next);
    }
    const float* b0 = bias + (size_t)(l * NET + 0) * NH;
    const float* b1 = bias + (size_t)(l * NET + 1) * NH;
    const float* b2 = bias + (size_t)(l * NET + 2) * NH;
    bias_relu_kernel<<<(N_NODES * NH + 255) / 256, 256, 0, stream>>>(h_next, b0, b1, b2,
                                                                     l != LAYERS - 1);
    h_cur = h_next;
    h_next = (h_next == h0) ? h1 : h0;
  }
  linear_kernel<<<N_NODES, 256, 0, stream>>>(h_cur, lin_w, lin_b, out);
}

// Round 2
// 3424.786 us; speedup vs baseline: 2.4753x; 2.4753x over previous
//
#include <hip/hip_runtime.h>
#include <hip/hip_bf16.h>
#include <math.h>

#define N_NODES 50000
#define NEDGE 800000
#define NET 3
#define LAYERS 3
#define HEADS 4
#define DHEAD 64
#define NH 256
#define NC 16
#define NEG_SLOPE 0.2f

// ---------------- GEMM: C[M x 256] = A[M x 256] @ B[256 x 256], fp32 ----------------
__global__ __launch_bounds__(256) void gemm_f32(const float* __restrict__ A,
                                                const float* __restrict__ B,
                                                float* __restrict__ C, int M) {
  __shared__ float As[16][65];
  __shared__ float Bs[16][65];
  const int K = 256;
  int bm = blockIdx.x * 64;
  int bn = blockIdx.y * 64;
  int tid = threadIdx.x;
  int tx = tid & 15, ty = tid >> 4;
  float acc[4][4];
#pragma unroll
  for (int i = 0; i < 4; i++)
#pragma unroll
    for (int j = 0; j < 4; j++) acc[i][j] = 0.f;

  for (int k0 = 0; k0 < K; k0 += 16) {
#pragma unroll
    for (int i = 0; i < 4; i++) {
      int idx = tid + i * 256;          // A tile 64 rows x 16 k
      int r = idx >> 4, c = idx & 15;
      int row = bm + r;
      As[c][r] = (row < M) ? A[(size_t)row * K + k0 + c] : 0.f;
    }
#pragma unroll
    for (int i = 0; i < 4; i++) {
      int idx = tid + i * 256;          // B tile 16 k x 64 cols
      int r = idx >> 6, c = idx & 63;
      Bs[r][c] = B[(size_t)(k0 + r) * 256 + bn + c];
    }
    __syncthreads();
#pragma unroll
    for (int kk = 0; kk < 16; kk++) {
      float a[4], b[4];
#pragma unroll
      for (int i = 0; i < 4; i++) a[i] = As[kk][ty * 4 + i];
#pragma unroll
      for (int j = 0; j < 4; j++) b[j] = Bs[kk][tx * 4 + j];
#pragma unroll
      for (int i = 0; i < 4; i++)
#pragma unroll
        for (int j = 0; j < 4; j++) acc[i][j] = fmaf(a[i], b[j], acc[i][j]);
    }
    __syncthreads();
  }
#pragma unroll
  for (int i = 0; i < 4; i++) {
    int row = bm + ty * 4 + i;
    if (row < M) {
#pragma unroll
      for (int j = 0; j < 4; j++) C[(size_t)row * 256 + bn + tx * 4 + j] = acc[i][j];
    }
  }
}

// ---------------- el/er: per-node per-head dot of z with attn vectors ----------------
__global__ __launch_bounds__(256) void scores_kernel(const float* __restrict__ z,
                                                     const float* __restrict__ al,
                                                     const float* __restrict__ ar,
                                                     float* __restrict__ el,
                                                     float* __restrict__ er) {
  int n = blockIdx.x;
  int j = threadIdx.x;                  // 0..255 ; head = j>>6
  float zv = z[(size_t)n * NH + j];
  float l = zv * al[j];
  float r = zv * ar[j];
#pragma unroll
  for (int off = 32; off > 0; off >>= 1) {
    l += __shfl_down(l, off, 64);
    r += __shfl_down(r, off, 64);
  }
  if ((j & 63) == 0) {
    int h = j >> 6;
    el[n * HEADS + h] = l;
    er[n * HEADS + h] = r;
  }
}

__device__ inline float leaky(float v) { return v > 0.f ? v : NEG_SLOPE * v; }

// ---------------- CSR build ----------------
__global__ void deg_kernel(const int* __restrict__ dst, int* __restrict__ deg) {
  int e = blockIdx.x * blockDim.x + threadIdx.x;
  if (e < NEDGE) atomicAdd(&deg[dst[e]], 1);
}

// single-block exclusive scan: rowptr[0]=0, rowptr[i+1]=sum_{<=i} deg
__global__ __launch_bounds__(1024) void scan_kernel(const int* __restrict__ deg,
                                                    int* __restrict__ rowptr) {
  __shared__ int wsum[16];
  __shared__ int carry_s;
  int tid = threadIdx.x;
  int lane = tid & 63, wv = tid >> 6;
  if (tid == 0) { carry_s = 0; rowptr[0] = 0; }
  __syncthreads();
  for (int base = 0; base < N_NODES; base += 1024) {
    int i = base + tid;
    int v = (i < N_NODES) ? deg[i] : 0;
    int x = v;
#pragma unroll
    for (int off = 1; off < 64; off <<= 1) {
      int y = __shfl_up(x, off, 64);
      if (lane >= off) x += y;
    }
    if (lane == 63) wsum[wv] = x;
    __syncthreads();
    if (wv == 0 && lane < 16) {
      int s = wsum[lane];
#pragma unroll
      for (int off = 1; off < 16; off <<= 1) {
        int y = __shfl_up(s, off, 16);
        if (lane >= off) s += y;
      }
      wsum[lane] = s;
    }
    __syncthreads();
    int waveoff = (wv > 0) ? wsum[wv - 1] : 0;
    int incl = x + waveoff + carry_s;
    if (i < N_NODES) rowptr[i + 1] = incl;
    __syncthreads();
    if (tid == 1023) carry_s = incl;
    __syncthreads();
  }
}

__global__ void scatter_kernel(const int* __restrict__ src, const int* __restrict__ dst,
                               int* __restrict__ cursor, int* __restrict__ col) {
  int e = blockIdx.x * blockDim.x + threadIdx.x;
  if (e < NEDGE) {
    int d = dst[e];
    int pos = atomicAdd(&cursor[d], 1);
    col[pos] = src[e];
  }
}

// ---------------- fused per-dst-node softmax + aggregation (no atomics) ----------------
// one block (256 thr) per dst node; thread j -> feature j, head j>>6 (wave == head)
__global__ __launch_bounds__(256) void agg_kernel(const int* __restrict__ rowptr,
                                                  const int* __restrict__ col,
                                                  const float* __restrict__ el,
                                                  const float* __restrict__ er,
                                                  const float* __restrict__ z,
                                                  float* __restrict__ hout,
                                                  const float* __restrict__ b0,
                                                  const float* __restrict__ b1,
                                                  const float* __restrict__ b2,
                                                  int first, int addbias, int dorelu) {
  int n = blockIdx.x;
  int j = threadIdx.x;
  int h = j >> 6, lane = j & 63;
  int rs = rowptr[n];
  int deg = rowptr[n + 1] - rs;

  __shared__ int s_idx[64];
  __shared__ float s_alpha[4][64];

  float erh = er[n * HEADS + h];

  // pass 1: per-head max over incoming edges
  float mx = -INFINITY;
  for (int k = lane; k < deg; k += 64) {
    int s = col[rs + k];
    mx = fmaxf(mx, leaky(el[s * HEADS + h] + erh));
  }
#pragma unroll
  for (int off = 32; off > 0; off >>= 1) mx = fmaxf(mx, __shfl_xor(mx, off, 64));

  // pass 2: denom
  float sm = 0.f;
  for (int k = lane; k < deg; k += 64) {
    int s = col[rs + k];
    sm += expf(leaky(el[s * HEADS + h] + erh) - mx);
  }
#pragma unroll
  for (int off = 32; off > 0; off >>= 1) sm += __shfl_xor(sm, off, 64);
  float inv = (deg > 0) ? 1.f / sm : 0.f;

  // pass 3: weighted gather of z[src] rows
  float acc = 0.f;
  for (int c0 = 0; c0 < deg; c0 += 64) {
    int kc = min(64, deg - c0);
    if (lane < kc) {
      int s = col[rs + c0 + lane];
      if (h == 0) s_idx[lane] = s;
      s_alpha[h][lane] = expf(leaky(el[s * HEADS + h] + erh) - mx) * inv;
    }
    __syncthreads();
    int k = 0;
    for (; k + 3 < kc; k += 4) {
      float z0 = z[(size_t)s_idx[k + 0] * NH + j];
      float z1 = z[(size_t)s_idx[k + 1] * NH + j];
      float z2 = z[(size_t)s_idx[k + 2] * NH + j];
      float z3 = z[(size_t)s_idx[k + 3] * NH + j];
      acc = fmaf(s_alpha[h][k + 0], z0, acc);
      acc = fmaf(s_alpha[h][k + 1], z1, acc);
      acc = fmaf(s_alpha[h][k + 2], z2, acc);
      acc = fmaf(s_alpha[h][k + 3], z3, acc);
    }
    for (; k < kc; k++) acc = fmaf(s_alpha[h][k], z[(size_t)s_idx[k] * NH + j], acc);
    __syncthreads();
  }

  size_t oi = (size_t)n * NH + j;
  float v = acc;
  if (!first) v += hout[oi];
  if (addbias) v += b0[j] + b1[j] + b2[j];
  if (dorelu && v < 0.f) v = 0.f;
  hout[oi] = v;
}

// out[n][c] = sum_j h[n][j] * w[j][c] + b[c]
__global__ __launch_bounds__(256) void linear_kernel(const float* __restrict__ h,
                                                     const float* __restrict__ w,
                                                     const float* __restrict__ b,
                                                     float* __restrict__ out) {
  __shared__ float part[16][17];
  int n = blockIdx.x;
  int t = threadIdx.x;
  int c = t & 15, p = t >> 4;
  float sum = 0.f;
#pragma unroll
  for (int q = 0; q < 16; q++) {
    int j = p * 16 + q;
    sum = fmaf(h[(size_t)n * NH + j], w[j * NC + c], sum);
  }
  part[p][c] = sum;
  __syncthreads();
  if (t < 16) {
    float s = 0.f;
#pragma unroll
    for (int p2 = 0; p2 < 16; p2++) s += part[p2][t];
    out[n * NC + t] = s + b[t];
  }
}

extern "C" void kernel_launch(void* const* d_in, const int* in_sizes, int n_in,
                              void* d_out, int out_size, void* d_ws, size_t ws_size,
                              hipStream_t stream) {
  const float* x      = (const float*)d_in[0];
  const int*   src    = (const int*)d_in[1];
  const int*   dst    = (const int*)d_in[2];
  const float* W      = (const float*)d_in[3];
  const float* attn_l = (const float*)d_in[4];
  const float* attn_r = (const float*)d_in[5];
  const float* bias   = (const float*)d_in[6];
  const float* lin_w  = (const float*)d_in[7];
  const float* lin_b  = (const float*)d_in[8];
  float* out = (float*)d_out;

  char* ws = (char*)d_ws;
  size_t off = 0;
  float* h0 = (float*)(ws + off); off += (size_t)N_NODES * NH * 4;
  float* h1 = (float*)(ws + off); off += (size_t)N_NODES * NH * 4;
  float* z  = (float*)(ws + off); off += (size_t)N_NODES * NH * 4;
  float* el = (float*)(ws + off); off += (size_t)N_NODES * HEADS * 4;
  float* er = (float*)(ws + off); off += (size_t)N_NODES * HEADS * 4;
  int* rowptr[NET];
  for (int t = 0; t < NET; t++) { rowptr[t] = (int*)(ws + off); off += (size_t)(N_NODES + 1) * 4; }
  int* col[NET];
  for (int t = 0; t < NET; t++) { col[t] = (int*)(ws + off); off += (size_t)NEDGE * 4; }
  int* deg    = (int*)(ws + off); off += (size_t)N_NODES * 4;
  int* cursor = (int*)(ws + off); off += (size_t)N_NODES * 4;

  // ---- build dst-CSR per etype (graph is call-invariant, rebuilt every call) ----
  for (int t = 0; t < NET; t++) {
    const int* d_t = dst + (size_t)t * NEDGE;
    const int* s_t = src + (size_t)t * NEDGE;
    hipMemsetAsync(deg, 0, (size_t)N_NODES * 4, stream);
    deg_kernel<<<(NEDGE + 255) / 256, 256, 0, stream>>>(d_t, deg);
    scan_kernel<<<1, 1024, 0, stream>>>(deg, rowptr[t]);
    hipMemcpyAsync(cursor, rowptr[t], (size_t)N_NODES * 4, hipMemcpyDeviceToDevice, stream);
    scatter_kernel<<<(NEDGE + 255) / 256, 256, 0, stream>>>(s_t, d_t, cursor, col[t]);
  }

  const float* h_cur = x;
  float* h_next = h0;

  for (int l = 0; l < LAYERS; l++) {
    const float* b0 = bias + (size_t)(l * NET + 0) * NH;
    const float* b1 = bias + (size_t)(l * NET + 1) * NH;
    const float* b2 = bias + (size_t)(l * NET + 2) * NH;
    for (int t = 0; t < NET; t++) {
      const float* Wlt = W      + (size_t)(l * NET + t) * NH * NH;
      const float* al  = attn_l + (size_t)(l * NET + t) * HEADS * DHEAD;
      const float* ar  = attn_r + (size_t)(l * NET + t) * HEADS * DHEAD;

      dim3 gg((N_NODES + 63) / 64, NH / 64);
      gemm_f32<<<gg, 256, 0, stream>>>(h_cur, Wlt, z, N_NODES);
      scores_kernel<<<N_NODES, 256, 0, stream>>>(z, al, ar, el, er);
      agg_kernel<<<N_NODES, 256, 0, stream>>>(rowptr[t], col[t], el, er, z, h_next,
                                              b0, b1, b2,
                                              t == 0, t == NET - 1,
                                              (t == NET - 1) && (l != LAYERS - 1));
    }
    h_cur = h_next;
    h_next = (h_next == h0) ? h1 : h0;
  }
  linear_kernel<<<N_NODES, 256, 0, stream>>>(h_cur, lin_w, lin_b, out);
}

// Round 6
// 2523.986 us; speedup vs baseline: 3.3587x; 1.3569x over previous
//
#include <hip/hip_runtime.h>
#include <hip/hip_bf16.h>
#include <math.h>

#define N_NODES 50000
#define NEDGE 800000
#define NET 3
#define LAYERS 3
#define HEADS 4
#define DHEAD 64
#define NH 256
#define NC 16
#define NEG_SLOPE 0.2f
#define MPAD 50048   // 782 * 64

typedef __attribute__((ext_vector_type(8))) short short8;
typedef __attribute__((ext_vector_type(4))) float f32x4;
typedef __attribute__((ext_vector_type(4))) _Float16 half4;

#define GLDS16(gp, lp) \
  __builtin_amdgcn_global_load_lds((const __attribute__((address_space(1))) void*)(gp), \
                                   (__attribute__((address_space(3))) void*)(lp), 16, 0, 0)

__device__ inline unsigned short f2bf(float x) {
  unsigned u = __float_as_uint(x);
  unsigned r = (u + 0x7FFFu + ((u >> 16) & 1u)) >> 16;
  return (unsigned short)r;
}
__device__ inline float bf2f(unsigned short h) { return __uint_as_float(((unsigned)h) << 16); }

// ---- split W into hi/lo bf16, transposed to [n][k] for MFMA B-operand ----
__global__ void split_transpose_W(const float* __restrict__ W,
                                  unsigned short* __restrict__ WhT,
                                  unsigned short* __restrict__ WlT) {
  int i = blockIdx.x * blockDim.x + threadIdx.x;
  if (i >= LAYERS * NET * NH * NH) return;
  int mat = i >> 16, rem = i & 65535;
  int n = rem >> 8, k = rem & 255;
  float v = W[(size_t)mat * 65536 + k * 256 + n];
  unsigned short hi = f2bf(v);
  unsigned short lo = f2bf(v - bf2f(hi));
  WhT[(size_t)mat * 65536 + n * 256 + k] = hi;
  WlT[(size_t)mat * 65536 + n * 256 + k] = lo;
}

// ---- split activations into hi/lo bf16 ----
__global__ void split_kernel(const float* __restrict__ in, unsigned short* __restrict__ hi,
                             unsigned short* __restrict__ lo) {
  int i = blockIdx.x * blockDim.x + threadIdx.x;
  if (i >= N_NODES * NH / 4) return;
  float4 v = ((const float4*)in)[i];
  ushort4 h, l;
  h.x = f2bf(v.x); l.x = f2bf(v.x - bf2f(h.x));
  h.y = f2bf(v.y); l.y = f2bf(v.y - bf2f(h.y));
  h.z = f2bf(v.z); l.z = f2bf(v.z - bf2f(h.z));
  h.w = f2bf(v.w); l.w = f2bf(v.w - bf2f(h.w));
  ((ushort4*)hi)[i] = h;
  ((ushort4*)lo)[i] = l;
}

// ---- split-bf16 MFMA GEMM: z[M x 256] = A @ W (fp16 out), fused el/er epilogue ----
// block = 64 rows x 256 cols, 4 waves, wave w handles cols [w*64, w*64+64) == head w
__global__ __launch_bounds__(256) void gemm_split(const unsigned short* __restrict__ Ah,
                                                  const unsigned short* __restrict__ Al,
                                                  const unsigned short* __restrict__ BhT,
                                                  const unsigned short* __restrict__ BlT,
                                                  const float* __restrict__ al,
                                                  const float* __restrict__ ar,
                                                  _Float16* __restrict__ zh,
                                                  float* __restrict__ el,
                                                  float* __restrict__ er, int M) {
  __shared__ unsigned short lds[20480];  // Ah 64x32 | Al 64x32 | BhT 256x32 | BlT 256x32
  unsigned short* sAh = lds;
  unsigned short* sAl = lds + 2048;
  unsigned short* sBh = lds + 4096;
  unsigned short* sBl = lds + 12288;

  int tid = threadIdx.x;
  int w = tid >> 6, lane = tid & 63;
  int r16 = lane & 15, rk = lane >> 4;
  int bm = blockIdx.x * 64;

  // staging positions: A slot tid -> row tid>>2, col (tid&3)*8 ; B slot tid+i*256
  int arow = tid >> 2, acol = (tid & 3) * 8;
  const unsigned short* pAh = Ah + (size_t)(bm + arow) * 256 + acol;
  const unsigned short* pAl = Al + (size_t)(bm + arow) * 256 + acol;

  f32x4 acc[4][4];
#pragma unroll
  for (int m = 0; m < 4; m++)
#pragma unroll
    for (int n = 0; n < 4; n++) acc[m][n] = (f32x4){0.f, 0.f, 0.f, 0.f};

  char* aldsA = (char*)lds + (size_t)w * 1024;          // wave base for A (slots w*64..)

#pragma unroll
  for (int k0 = 0; k0 < 8; k0++) {
    // ---- stage tiles (global -> LDS, 16B per lane, linear dest) ----
    GLDS16(pAh + k0 * 32, aldsA);
    GLDS16(pAl + k0 * 32, (char*)sAl + (size_t)w * 1024);
#pragma unroll
    for (int i = 0; i < 4; i++) {
      int slot = tid + i * 256;
      int nrow = slot >> 2, kcol = (slot & 3) * 8;
      size_t go = (size_t)nrow * 256 + k0 * 32 + kcol;
      char* lb = (char*)sBh + ((size_t)w * 64 + (size_t)i * 256) * 16;
      char* lb2 = (char*)sBl + ((size_t)w * 64 + (size_t)i * 256) * 16;
      GLDS16(BhT + go, lb);
      GLDS16(BlT + go, lb2);
    }
    __syncthreads();

    // ---- fragments ----
    short8 a_h[4], a_l[4], b_h[4], b_l[4];
#pragma unroll
    for (int m = 0; m < 4; m++) {
      a_h[m] = *(const short8*)&sAh[(m * 16 + r16) * 32 + rk * 8];
      a_l[m] = *(const short8*)&sAl[(m * 16 + r16) * 32 + rk * 8];
    }
#pragma unroll
    for (int n = 0; n < 4; n++) {
      int col = w * 64 + n * 16 + r16;
      b_h[n] = *(const short8*)&sBh[col * 32 + rk * 8];
      b_l[n] = *(const short8*)&sBl[col * 32 + rk * 8];
    }
#pragma unroll
    for (int m = 0; m < 4; m++)
#pragma unroll
      for (int n = 0; n < 4; n++) {
        acc[m][n] = __builtin_amdgcn_mfma_f32_16x16x32_bf16(a_h[m], b_h[n], acc[m][n], 0, 0, 0);
        acc[m][n] = __builtin_amdgcn_mfma_f32_16x16x32_bf16(a_h[m], b_l[n], acc[m][n], 0, 0, 0);
        acc[m][n] = __builtin_amdgcn_mfma_f32_16x16x32_bf16(a_l[m], b_h[n], acc[m][n], 0, 0, 0);
      }
    __syncthreads();
  }

  // ---- C write (fp16): row = bm + m*16 + rk*4 + r, col = w*64 + n*16 + r16 ----
#pragma unroll
  for (int m = 0; m < 4; m++) {
    int row0 = bm + m * 16 + rk * 4;
#pragma unroll
    for (int n = 0; n < 4; n++) {
      int col = w * 64 + n * 16 + r16;
#pragma unroll
      for (int r = 0; r < 4; r++) {
        int row = row0 + r;
        if (row < M) zh[(size_t)row * 256 + col] = (_Float16)acc[m][n][r];
      }
    }
  }

  // ---- fused el/er: head w = cols [w*64, w*64+64) ----
  float alv[4], arv[4];
#pragma unroll
  for (int n = 0; n < 4; n++) {
    alv[n] = al[w * 64 + n * 16 + r16];
    arv[n] = ar[w * 64 + n * 16 + r16];
  }
#pragma unroll
  for (int m = 0; m < 4; m++) {
#pragma unroll
    for (int r = 0; r < 4; r++) {
      float pl = 0.f, pr = 0.f;
#pragma unroll
      for (int n = 0; n < 4; n++) {
        float zv = acc[m][n][r];
        pl = fmaf(zv, alv[n], pl);
        pr = fmaf(zv, arv[n], pr);
      }
      pl += __shfl_xor(pl, 1, 64); pl += __shfl_xor(pl, 2, 64);
      pl += __shfl_xor(pl, 4, 64); pl += __shfl_xor(pl, 8, 64);
      pr += __shfl_xor(pr, 1, 64); pr += __shfl_xor(pr, 2, 64);
      pr += __shfl_xor(pr, 4, 64); pr += __shfl_xor(pr, 8, 64);
      int row = bm + m * 16 + rk * 4 + r;
      if (r16 == 0 && row < M) {
        el[row * HEADS + w] = pl;
        er[row * HEADS + w] = pr;
      }
    }
  }
}

__device__ inline float leaky(float v) { return v > 0.f ? v : NEG_SLOPE * v; }

// ---------------- CSR build ----------------
__global__ void deg_kernel(const int* __restrict__ dst, int* __restrict__ deg) {
  int e = blockIdx.x * blockDim.x + threadIdx.x;
  if (e < NEDGE) atomicAdd(&deg[dst[e]], 1);
}

__global__ __launch_bounds__(1024) void scan_kernel(const int* __restrict__ deg,
                                                    int* __restrict__ rowptr) {
  __shared__ int wsum[16];
  __shared__ int carry_s;
  int tid = threadIdx.x;
  int lane = tid & 63, wv = tid >> 6;
  if (tid == 0) { carry_s = 0; rowptr[0] = 0; }
  __syncthreads();
  for (int base = 0; base < N_NODES; base += 1024) {
    int i = base + tid;
    int v = (i < N_NODES) ? deg[i] : 0;
    int x = v;
#pragma unroll
    for (int off = 1; off < 64; off <<= 1) {
      int y = __shfl_up(x, off, 64);
      if (lane >= off) x += y;
    }
    if (lane == 63) wsum[wv] = x;
    __syncthreads();
    if (wv == 0 && lane < 16) {
      int s = wsum[lane];
#pragma unroll
      for (int off = 1; off < 16; off <<= 1) {
        int y = __shfl_up(s, off, 16);
        if (lane >= off) s += y;
      }
      wsum[lane] = s;
    }
    __syncthreads();
    int waveoff = (wv > 0) ? wsum[wv - 1] : 0;
    int incl = x + waveoff + carry_s;
    if (i < N_NODES) rowptr[i + 1] = incl;
    __syncthreads();
    if (tid == 1023) carry_s = incl;
    __syncthreads();
  }
}

__global__ void scatter_kernel(const int* __restrict__ src, const int* __restrict__ dst,
                               int* __restrict__ cursor, int* __restrict__ col) {
  int e = blockIdx.x * blockDim.x + threadIdx.x;
  if (e < NEDGE) {
    int d = dst[e];
    int pos = atomicAdd(&cursor[d], 1);
    col[pos] = src[e];
  }
}

// ---------------- fused per-dst-node softmax + aggregation ----------------
// one wave per dst node; lane owns features [lane*4, lane*4+4), head = lane>>4
__global__ __launch_bounds__(256) void agg_kernel(const int* __restrict__ rowptr,
                                                  const int* __restrict__ col,
                                                  const float* __restrict__ el,
                                                  const float* __restrict__ er,
                                                  const _Float16* __restrict__ zh,
                                                  float* __restrict__ hout,
                                                  const float* __restrict__ b0,
                                                  const float* __restrict__ b1,
                                                  const float* __restrict__ b2,
                                                  int first, int addbias, int dorelu) {
  int wv = threadIdx.x >> 6, lane = threadIdx.x & 63;
  int n = blockIdx.x * 4 + wv;
  int h = lane >> 4;
  int f0 = lane * 4;
  int rs = rowptr[n];
  int deg = rowptr[n + 1] - rs;
  float erh = er[n * HEADS + h];

  // pass 1: online max + sum (per lane; lanes of same head duplicate — no reduce needed)
  float mx = -INFINITY, sm = 0.f;
  for (int k = 0; k < deg; k++) {
    int s = col[rs + k];
    float v = leaky(el[s * HEADS + h] + erh);
    if (v > mx) {
      sm = sm * __expf(mx - v);
      mx = v;
      sm += 1.f;
    } else {
      sm += __expf(v - mx);
    }
  }
  float inv = (deg > 0) ? 1.f / sm : 0.f;

  // pass 2: weighted gather of z rows (half4 = 8B per lane, 512B per row per wave)
  float a0 = 0.f, a1 = 0.f, a2 = 0.f, a3 = 0.f;
  for (int k = 0; k < deg; k++) {
    int s = col[rs + k];
    float alpha = __expf(leaky(el[s * HEADS + h] + erh) - mx) * inv;
    half4 v = *(const half4*)&zh[(size_t)s * NH + f0];
    a0 = fmaf(alpha, (float)v.x, a0);
    a1 = fmaf(alpha, (float)v.y, a1);
    a2 = fmaf(alpha, (float)v.z, a2);
    a3 = fmaf(alpha, (float)v.w, a3);
  }

  size_t oi = (size_t)n * NH + f0;
  float4 vo;
  vo.x = a0; vo.y = a1; vo.z = a2; vo.w = a3;
  if (!first) {
    float4 prev = *(const float4*)&hout[oi];
    vo.x += prev.x; vo.y += prev.y; vo.z += prev.z; vo.w += prev.w;
  }
  if (addbias) {
    vo.x += b0[f0 + 0] + b1[f0 + 0] + b2[f0 + 0];
    vo.y += b0[f0 + 1] + b1[f0 + 1] + b2[f0 + 1];
    vo.z += b0[f0 + 2] + b1[f0 + 2] + b2[f0 + 2];
    vo.w += b0[f0 + 3] + b1[f0 + 3] + b2[f0 + 3];
  }
  if (dorelu) {
    vo.x = fmaxf(vo.x, 0.f); vo.y = fmaxf(vo.y, 0.f);
    vo.z = fmaxf(vo.z, 0.f); vo.w = fmaxf(vo.w, 0.f);
  }
  *(float4*)&hout[oi] = vo;
}

__global__ __launch_bounds__(256) void linear_kernel(const float* __restrict__ h,
                                                     const float* __restrict__ w,
                                                     const float* __restrict__ b,
                                                     float* __restrict__ out) {
  __shared__ float part[16][17];
  int n = blockIdx.x;
  int t = threadIdx.x;
  int c = t & 15, p = t >> 4;
  float sum = 0.f;
#pragma unroll
  for (int q = 0; q < 16; q++) {
    int j = p * 16 + q;
    sum = fmaf(h[(size_t)n * NH + j], w[j * NC + c], sum);
  }
  part[p][c] = sum;
  __syncthreads();
  if (t < 16) {
    float s = 0.f;
#pragma unroll
    for (int p2 = 0; p2 < 16; p2++) s += part[p2][t];
    out[n * NC + t] = s + b[t];
  }
}

extern "C" void kernel_launch(void* const* d_in, const int* in_sizes, int n_in,
                              void* d_out, int out_size, void* d_ws, size_t ws_size,
                              hipStream_t stream) {
  const float* x      = (const float*)d_in[0];
  const int*   src    = (const int*)d_in[1];
  const int*   dst    = (const int*)d_in[2];
  const float* W      = (const float*)d_in[3];
  const float* attn_l = (const float*)d_in[4];
  const float* attn_r = (const float*)d_in[5];
  const float* bias   = (const float*)d_in[6];
  const float* lin_w  = (const float*)d_in[7];
  const float* lin_b  = (const float*)d_in[8];
  float* out = (float*)d_out;

  char* ws = (char*)d_ws;
  size_t off = 0;
  float* h  = (float*)(ws + off); off += (size_t)N_NODES * NH * 4;
  _Float16* zh = (_Float16*)(ws + off); off += (size_t)N_NODES * NH * 2;
  unsigned short* Ah = (unsigned short*)(ws + off); off += (size_t)MPAD * NH * 2;
  unsigned short* Al = (unsigned short*)(ws + off); off += (size_t)MPAD * NH * 2;
  unsigned short* WhT = (unsigned short*)(ws + off); off += (size_t)LAYERS * NET * NH * NH * 2;
  unsigned short* WlT = (unsigned short*)(ws + off); off += (size_t)LAYERS * NET * NH * NH * 2;
  float* el = (float*)(ws + off); off += (size_t)N_NODES * HEADS * 4;
  float* er = (float*)(ws + off); off += (size_t)N_NODES * HEADS * 4;
  int* rowptr[NET];
  for (int t = 0; t < NET; t++) { rowptr[t] = (int*)(ws + off); off += (size_t)(N_NODES + 1) * 4; }
  int* colA[NET];
  for (int t = 0; t < NET; t++) { colA[t] = (int*)(ws + off); off += (size_t)NEDGE * 4; }
  int* deg    = (int*)(ws + off); off += (size_t)N_NODES * 4;
  int* cursor = (int*)(ws + off); off += (size_t)N_NODES * 4;

  // ---- build dst-CSR per etype (graph is call-invariant) ----
  for (int t = 0; t < NET; t++) {
    const int* d_t = dst + (size_t)t * NEDGE;
    const int* s_t = src + (size_t)t * NEDGE;
    hipMemsetAsync(deg, 0, (size_t)N_NODES * 4, stream);
    deg_kernel<<<(NEDGE + 255) / 256, 256, 0, stream>>>(d_t, deg);
    scan_kernel<<<1, 1024, 0, stream>>>(deg, rowptr[t]);
    hipMemcpyAsync(cursor, rowptr[t], (size_t)N_NODES * 4, hipMemcpyDeviceToDevice, stream);
    scatter_kernel<<<(NEDGE + 255) / 256, 256, 0, stream>>>(s_t, d_t, cursor, colA[t]);
  }

  // ---- split + transpose all weights once ----
  split_transpose_W<<<(LAYERS * NET * NH * NH + 255) / 256, 256, 0, stream>>>(W, WhT, WlT);

  for (int l = 0; l < LAYERS; l++) {
    const float* b0 = bias + (size_t)(l * NET + 0) * NH;
    const float* b1 = bias + (size_t)(l * NET + 1) * NH;
    const float* b2 = bias + (size_t)(l * NET + 2) * NH;

    const float* h_cur = (l == 0) ? x : h;
    split_kernel<<<(N_NODES * NH / 4 + 255) / 256, 256, 0, stream>>>(h_cur, Ah, Al);

    for (int t = 0; t < NET; t++) {
      const unsigned short* Bh = WhT + (size_t)(l * NET + t) * NH * NH;
      const unsigned short* Bl = WlT + (size_t)(l * NET + t) * NH * NH;
      const float* al = attn_l + (size_t)(l * NET + t) * HEADS * DHEAD;
      const float* ar = attn_r + (size_t)(l * NET + t) * HEADS * DHEAD;

      gemm_split<<<MPAD / 64, 256, 0, stream>>>(Ah, Al, Bh, Bl, al, ar, zh, el, er, N_NODES);
      agg_kernel<<<N_NODES / 4, 256, 0, stream>>>(rowptr[t], colA[t], el, er, zh, h,
                                                  b0, b1, b2,
                                                  t == 0, t == NET - 1,
                                                  (t == NET - 1) && (l != LAYERS - 1));
    }
  }
  linear_kernel<<<N_NODES, 256, 0, stream>>>(h, lin_w, lin_b, out);
}

// Round 7
// 1583.261 us; speedup vs baseline: 5.3543x; 1.5942x over previous
//
#include <hip/hip_runtime.h>
#include <hip/hip_bf16.h>
#include <math.h>

#define N_NODES 50000
#define NEDGE 800000
#define NET 3
#define LAYERS 3
#define HEADS 4
#define DHEAD 64
#define NH 256
#define NC 16
#define NEG_SLOPE 0.2f
#define MPAD 50048   // 782 * 64

typedef __attribute__((ext_vector_type(8))) short short8;
typedef __attribute__((ext_vector_type(4))) float f32x4;
typedef __attribute__((ext_vector_type(8))) _Float16 half8;

#define GLDS16(gp, lp) \
  __builtin_amdgcn_global_load_lds((const __attribute__((address_space(1))) void*)(gp), \
                                   (__attribute__((address_space(3))) void*)(lp), 16, 0, 0)

__device__ inline unsigned short f2bf(float x) {
  unsigned u = __float_as_uint(x);
  unsigned r = (u + 0x7FFFu + ((u >> 16) & 1u)) >> 16;
  return (unsigned short)r;
}
__device__ inline float bf2f(unsigned short h) { return __uint_as_float(((unsigned)h) << 16); }

// ---- split W into hi/lo bf16, transposed to [n][k] for MFMA B-operand ----
__global__ void split_transpose_W(const float* __restrict__ W,
                                  unsigned short* __restrict__ WhT,
                                  unsigned short* __restrict__ WlT) {
  int i = blockIdx.x * blockDim.x + threadIdx.x;
  if (i >= LAYERS * NET * NH * NH) return;
  int mat = i >> 16, rem = i & 65535;
  int n = rem >> 8, k = rem & 255;
  float v = W[(size_t)mat * 65536 + k * 256 + n];
  unsigned short hi = f2bf(v);
  unsigned short lo = f2bf(v - bf2f(hi));
  WhT[(size_t)mat * 65536 + n * 256 + k] = hi;
  WlT[(size_t)mat * 65536 + n * 256 + k] = lo;
}

// ---- split activations into hi/lo bf16 ----
__global__ void split_kernel(const float* __restrict__ in, unsigned short* __restrict__ hi,
                             unsigned short* __restrict__ lo) {
  int i = blockIdx.x * blockDim.x + threadIdx.x;
  if (i >= N_NODES * NH / 4) return;
  float4 v = ((const float4*)in)[i];
  ushort4 h, l;
  h.x = f2bf(v.x); l.x = f2bf(v.x - bf2f(h.x));
  h.y = f2bf(v.y); l.y = f2bf(v.y - bf2f(h.y));
  h.z = f2bf(v.z); l.z = f2bf(v.z - bf2f(h.z));
  h.w = f2bf(v.w); l.w = f2bf(v.w - bf2f(h.w));
  ((ushort4*)hi)[i] = h;
  ((ushort4*)lo)[i] = l;
}

// ---- split-bf16 MFMA GEMM: z[M x 256] = A @ W (fp16 out), fused el/er epilogue ----
// block = 64 rows x 256 cols, 4 waves, wave w handles cols [w*64, w*64+64) == head w
__global__ __launch_bounds__(256) void gemm_split(const unsigned short* __restrict__ Ah,
                                                  const unsigned short* __restrict__ Al,
                                                  const unsigned short* __restrict__ BhT,
                                                  const unsigned short* __restrict__ BlT,
                                                  const float* __restrict__ al,
                                                  const float* __restrict__ ar,
                                                  _Float16* __restrict__ zh,
                                                  float* __restrict__ el,
                                                  float* __restrict__ er, int M) {
  __shared__ unsigned short lds[20480];  // Ah 64x32 | Al 64x32 | BhT 256x32 | BlT 256x32
  unsigned short* sAh = lds;
  unsigned short* sAl = lds + 2048;
  unsigned short* sBh = lds + 4096;
  unsigned short* sBl = lds + 12288;

  int tid = threadIdx.x;
  int w = tid >> 6, lane = tid & 63;
  int r16 = lane & 15, rk = lane >> 4;
  int bm = blockIdx.x * 64;

  // staging positions: A slot tid -> row tid>>2, col (tid&3)*8 ; B slot tid+i*256
  int arow = tid >> 2, acol = (tid & 3) * 8;
  const unsigned short* pAh = Ah + (size_t)(bm + arow) * 256 + acol;
  const unsigned short* pAl = Al + (size_t)(bm + arow) * 256 + acol;

  f32x4 acc[4][4];
#pragma unroll
  for (int m = 0; m < 4; m++)
#pragma unroll
    for (int n = 0; n < 4; n++) acc[m][n] = (f32x4){0.f, 0.f, 0.f, 0.f};

  char* aldsA = (char*)lds + (size_t)w * 1024;          // wave base for A (slots w*64..)

#pragma unroll
  for (int k0 = 0; k0 < 8; k0++) {
    // ---- stage tiles (global -> LDS, 16B per lane, linear dest) ----
    GLDS16(pAh + k0 * 32, aldsA);
    GLDS16(pAl + k0 * 32, (char*)sAl + (size_t)w * 1024);
#pragma unroll
    for (int i = 0; i < 4; i++) {
      int slot = tid + i * 256;
      int nrow = slot >> 2, kcol = (slot & 3) * 8;
      size_t go = (size_t)nrow * 256 + k0 * 32 + kcol;
      char* lb = (char*)sBh + ((size_t)w * 64 + (size_t)i * 256) * 16;
      char* lb2 = (char*)sBl + ((size_t)w * 64 + (size_t)i * 256) * 16;
      GLDS16(BhT + go, lb);
      GLDS16(BlT + go, lb2);
    }
    __syncthreads();

    // ---- fragments ----
    short8 a_h[4], a_l[4], b_h[4], b_l[4];
#pragma unroll
    for (int m = 0; m < 4; m++) {
      a_h[m] = *(const short8*)&sAh[(m * 16 + r16) * 32 + rk * 8];
      a_l[m] = *(const short8*)&sAl[(m * 16 + r16) * 32 + rk * 8];
    }
#pragma unroll
    for (int n = 0; n < 4; n++) {
      int col = w * 64 + n * 16 + r16;
      b_h[n] = *(const short8*)&sBh[col * 32 + rk * 8];
      b_l[n] = *(const short8*)&sBl[col * 32 + rk * 8];
    }
#pragma unroll
    for (int m = 0; m < 4; m++)
#pragma unroll
      for (int n = 0; n < 4; n++) {
        acc[m][n] = __builtin_amdgcn_mfma_f32_16x16x32_bf16(a_h[m], b_h[n], acc[m][n], 0, 0, 0);
        acc[m][n] = __builtin_amdgcn_mfma_f32_16x16x32_bf16(a_h[m], b_l[n], acc[m][n], 0, 0, 0);
        acc[m][n] = __builtin_amdgcn_mfma_f32_16x16x32_bf16(a_l[m], b_h[n], acc[m][n], 0, 0, 0);
      }
    __syncthreads();
  }

  // ---- C write (fp16): row = bm + m*16 + rk*4 + r, col = w*64 + n*16 + r16 ----
#pragma unroll
  for (int m = 0; m < 4; m++) {
    int row0 = bm + m * 16 + rk * 4;
#pragma unroll
    for (int n = 0; n < 4; n++) {
      int col = w * 64 + n * 16 + r16;
#pragma unroll
      for (int r = 0; r < 4; r++) {
        int row = row0 + r;
        if (row < M) zh[(size_t)row * 256 + col] = (_Float16)acc[m][n][r];
      }
    }
  }

  // ---- fused el/er: head w = cols [w*64, w*64+64) ----
  float alv[4], arv[4];
#pragma unroll
  for (int n = 0; n < 4; n++) {
    alv[n] = al[w * 64 + n * 16 + r16];
    arv[n] = ar[w * 64 + n * 16 + r16];
  }
#pragma unroll
  for (int m = 0; m < 4; m++) {
#pragma unroll
    for (int r = 0; r < 4; r++) {
      float pl = 0.f, pr = 0.f;
#pragma unroll
      for (int n = 0; n < 4; n++) {
        float zv = acc[m][n][r];
        pl = fmaf(zv, alv[n], pl);
        pr = fmaf(zv, arv[n], pr);
      }
      pl += __shfl_xor(pl, 1, 64); pl += __shfl_xor(pl, 2, 64);
      pl += __shfl_xor(pl, 4, 64); pl += __shfl_xor(pl, 8, 64);
      pr += __shfl_xor(pr, 1, 64); pr += __shfl_xor(pr, 2, 64);
      pr += __shfl_xor(pr, 4, 64); pr += __shfl_xor(pr, 8, 64);
      int row = bm + m * 16 + rk * 4 + r;
      if (r16 == 0 && row < M) {
        el[row * HEADS + w] = pl;
        er[row * HEADS + w] = pr;
      }
    }
  }
}

__device__ inline float leaky(float v) { return v > 0.f ? v : NEG_SLOPE * v; }

// ---------------- CSR build ----------------
__global__ void deg_kernel(const int* __restrict__ dst, int* __restrict__ deg) {
  int e = blockIdx.x * blockDim.x + threadIdx.x;
  if (e < NEDGE) atomicAdd(&deg[dst[e]], 1);
}

__global__ __launch_bounds__(1024) void scan_kernel(const int* __restrict__ deg,
                                                    int* __restrict__ rowptr) {
  __shared__ int wsum[16];
  __shared__ int carry_s;
  int tid = threadIdx.x;
  int lane = tid & 63, wv = tid >> 6;
  if (tid == 0) { carry_s = 0; rowptr[0] = 0; }
  __syncthreads();
  for (int base = 0; base < N_NODES; base += 1024) {
    int i = base + tid;
    int v = (i < N_NODES) ? deg[i] : 0;
    int x = v;
#pragma unroll
    for (int off = 1; off < 64; off <<= 1) {
      int y = __shfl_up(x, off, 64);
      if (lane >= off) x += y;
    }
    if (lane == 63) wsum[wv] = x;
    __syncthreads();
    if (wv == 0 && lane < 16) {
      int s = wsum[lane];
#pragma unroll
      for (int off = 1; off < 16; off <<= 1) {
        int y = __shfl_up(s, off, 16);
        if (lane >= off) s += y;
      }
      wsum[lane] = s;
    }
    __syncthreads();
    int waveoff = (wv > 0) ? wsum[wv - 1] : 0;
    int incl = x + waveoff + carry_s;
    if (i < N_NODES) rowptr[i + 1] = incl;
    __syncthreads();
    if (tid == 1023) carry_s = incl;
    __syncthreads();
  }
}

__global__ void scatter_kernel(const int* __restrict__ src, const int* __restrict__ dst,
                               int* __restrict__ cursor, int* __restrict__ col) {
  int e = blockIdx.x * blockDim.x + threadIdx.x;
  if (e < NEDGE) {
    int d = dst[e];
    int pos = atomicAdd(&cursor[d], 1);
    col[pos] = src[e];
  }
}

// ---------------- fused per-dst-node softmax + aggregation ----------------
// one wave per dst node. Phase A: lane = (edge kk = lane&15, head = lane>>4):
// score 16 edges/iter, store unnormalized exp to LDS. Phase B: lanes split in 2
// halves, each half gathers one z row (half8 = 16B/lane), alphas from LDS.
// Normalization (1/sum) applied once at the end => exact for any degree.
__global__ __launch_bounds__(256) void agg_kernel(const int* __restrict__ rowptr,
                                                  const int* __restrict__ col,
                                                  const float* __restrict__ el,
                                                  const float* __restrict__ er,
                                                  const _Float16* __restrict__ zh,
                                                  float* __restrict__ hout,
                                                  const float* __restrict__ b0,
                                                  const float* __restrict__ b1,
                                                  const float* __restrict__ b2,
                                                  int first, int addbias, int dorelu) {
  __shared__ float s_alpha[4][128][4];
  __shared__ int s_col[4][128];

  int wv = threadIdx.x >> 6, lane = threadIdx.x & 63;
  int n = blockIdx.x * 4 + wv;
  int rs = rowptr[n];
  int deg = rowptr[n + 1] - rs;

  // phase-A lane mapping
  int kk = lane & 15, hh = lane >> 4;
  float erh = er[n * HEADS + hh];
  // phase-B lane mapping
  int which = lane >> 5, lj = lane & 31, fh = lj >> 3;

  float sm = 0.f;
  float a0 = 0.f, a1 = 0.f, a2 = 0.f, a3 = 0.f;
  float a4 = 0.f, a5 = 0.f, a6 = 0.f, a7 = 0.f;

  for (int s0 = 0; s0 < deg; s0 += 128) {
    int segN = min(128, deg - s0);
    // ---- phase A: score 16 edges x 4 heads per iteration ----
    for (int c0 = 0; c0 < segN; c0 += 16) {
      if (c0 + kk < segN) {
        int s = col[rs + s0 + c0 + kk];
        float a = __expf(leaky(el[s * HEADS + hh] + erh));
        sm += a;
        s_alpha[wv][c0 + kk][hh] = a;
        if (hh == 0) s_col[wv][c0 + kk] = s;
      }
    }
    // ---- phase B: gather 2 z rows per iteration ----
    for (int k = which; k < segN; k += 2) {
      float a = s_alpha[wv][k][fh];
      int s = s_col[wv][k];
      half8 v = *(const half8*)&zh[(size_t)s * NH + lj * 8];
      a0 = fmaf(a, (float)v[0], a0);
      a1 = fmaf(a, (float)v[1], a1);
      a2 = fmaf(a, (float)v[2], a2);
      a3 = fmaf(a, (float)v[3], a3);
      a4 = fmaf(a, (float)v[4], a4);
      a5 = fmaf(a, (float)v[5], a5);
      a6 = fmaf(a, (float)v[6], a6);
      a7 = fmaf(a, (float)v[7], a7);
    }
  }

  // reduce sum over the 16 edge-lanes of each head group (phase-A layout)
  sm += __shfl_xor(sm, 1, 64);
  sm += __shfl_xor(sm, 2, 64);
  sm += __shfl_xor(sm, 4, 64);
  sm += __shfl_xor(sm, 8, 64);
  float inv = (deg > 0) ? 1.f / sm : 0.f;
  // broadcast to phase-B layout: lane needs inv of head fh (lives at lane fh*16)
  float invb = __shfl(inv, fh * 16, 64);

  // merge the two edge-halves
  a0 += __shfl_xor(a0, 32, 64); a1 += __shfl_xor(a1, 32, 64);
  a2 += __shfl_xor(a2, 32, 64); a3 += __shfl_xor(a3, 32, 64);
  a4 += __shfl_xor(a4, 32, 64); a5 += __shfl_xor(a5, 32, 64);
  a6 += __shfl_xor(a6, 32, 64); a7 += __shfl_xor(a7, 32, 64);

  if (lane < 32) {
    int f0 = lj * 8;
    size_t oi = (size_t)n * NH + f0;
    float vo[8] = {a0 * invb, a1 * invb, a2 * invb, a3 * invb,
                   a4 * invb, a5 * invb, a6 * invb, a7 * invb};
    if (!first) {
      float4 p0 = *(const float4*)&hout[oi];
      float4 p1 = *(const float4*)&hout[oi + 4];
      vo[0] += p0.x; vo[1] += p0.y; vo[2] += p0.z; vo[3] += p0.w;
      vo[4] += p1.x; vo[5] += p1.y; vo[6] += p1.z; vo[7] += p1.w;
    }
    if (addbias) {
#pragma unroll
      for (int i = 0; i < 8; i++) vo[i] += b0[f0 + i] + b1[f0 + i] + b2[f0 + i];
    }
    if (dorelu) {
#pragma unroll
      for (int i = 0; i < 8; i++) vo[i] = fmaxf(vo[i], 0.f);
    }
    float4 o0 = {vo[0], vo[1], vo[2], vo[3]};
    float4 o1 = {vo[4], vo[5], vo[6], vo[7]};
    *(float4*)&hout[oi] = o0;
    *(float4*)&hout[oi + 4] = o1;
  }
}

__global__ __launch_bounds__(256) void linear_kernel(const float* __restrict__ h,
                                                     const float* __restrict__ w,
                                                     const float* __restrict__ b,
                                                     float* __restrict__ out) {
  __shared__ float part[16][17];
  int n = blockIdx.x;
  int t = threadIdx.x;
  int c = t & 15, p = t >> 4;
  float sum = 0.f;
#pragma unroll
  for (int q = 0; q < 16; q++) {
    int j = p * 16 + q;
    sum = fmaf(h[(size_t)n * NH + j], w[j * NC + c], sum);
  }
  part[p][c] = sum;
  __syncthreads();
  if (t < 16) {
    float s = 0.f;
#pragma unroll
    for (int p2 = 0; p2 < 16; p2++) s += part[p2][t];
    out[n * NC + t] = s + b[t];
  }
}

extern "C" void kernel_launch(void* const* d_in, const int* in_sizes, int n_in,
                              void* d_out, int out_size, void* d_ws, size_t ws_size,
                              hipStream_t stream) {
  const float* x      = (const float*)d_in[0];
  const int*   src    = (const int*)d_in[1];
  const int*   dst    = (const int*)d_in[2];
  const float* W      = (const float*)d_in[3];
  const float* attn_l = (const float*)d_in[4];
  const float* attn_r = (const float*)d_in[5];
  const float* bias   = (const float*)d_in[6];
  const float* lin_w  = (const float*)d_in[7];
  const float* lin_b  = (const float*)d_in[8];
  float* out = (float*)d_out;

  char* ws = (char*)d_ws;
  size_t off = 0;
  float* h  = (float*)(ws + off); off += (size_t)N_NODES * NH * 4;
  _Float16* zh = (_Float16*)(ws + off); off += (size_t)N_NODES * NH * 2;
  unsigned short* Ah = (unsigned short*)(ws + off); off += (size_t)MPAD * NH * 2;
  unsigned short* Al = (unsigned short*)(ws + off); off += (size_t)MPAD * NH * 2;
  unsigned short* WhT = (unsigned short*)(ws + off); off += (size_t)LAYERS * NET * NH * NH * 2;
  unsigned short* WlT = (unsigned short*)(ws + off); off += (size_t)LAYERS * NET * NH * NH * 2;
  float* el = (float*)(ws + off); off += (size_t)N_NODES * HEADS * 4;
  float* er = (float*)(ws + off); off += (size_t)N_NODES * HEADS * 4;
  int* rowptr[NET];
  for (int t = 0; t < NET; t++) { rowptr[t] = (int*)(ws + off); off += (size_t)(N_NODES + 1) * 4; }
  int* colA[NET];
  for (int t = 0; t < NET; t++) { colA[t] = (int*)(ws + off); off += (size_t)NEDGE * 4; }
  int* deg    = (int*)(ws + off); off += (size_t)N_NODES * 4;
  int* cursor = (int*)(ws + off); off += (size_t)N_NODES * 4;

  // ---- build dst-CSR per etype (graph is call-invariant) ----
  for (int t = 0; t < NET; t++) {
    const int* d_t = dst + (size_t)t * NEDGE;
    const int* s_t = src + (size_t)t * NEDGE;
    hipMemsetAsync(deg, 0, (size_t)N_NODES * 4, stream);
    deg_kernel<<<(NEDGE + 255) / 256, 256, 0, stream>>>(d_t, deg);
    scan_kernel<<<1, 1024, 0, stream>>>(deg, rowptr[t]);
    hipMemcpyAsync(cursor, rowptr[t], (size_t)N_NODES * 4, hipMemcpyDeviceToDevice, stream);
    scatter_kernel<<<(NEDGE + 255) / 256, 256, 0, stream>>>(s_t, d_t, cursor, colA[t]);
  }

  // ---- split + transpose all weights once ----
  split_transpose_W<<<(LAYERS * NET * NH * NH + 255) / 256, 256, 0, stream>>>(W, WhT, WlT);

  for (int l = 0; l < LAYERS; l++) {
    const float* b0 = bias + (size_t)(l * NET + 0) * NH;
    const float* b1 = bias + (size_t)(l * NET + 1) * NH;
    const float* b2 = bias + (size_t)(l * NET + 2) * NH;

    const float* h_cur = (l == 0) ? x : h;
    split_kernel<<<(N_NODES * NH / 4 + 255) / 256, 256, 0, stream>>>(h_cur, Ah, Al);

    for (int t = 0; t < NET; t++) {
      const unsigned short* Bh = WhT + (size_t)(l * NET + t) * NH * NH;
      const unsigned short* Bl = WlT + (size_t)(l * NET + t) * NH * NH;
      const float* al = attn_l + (size_t)(l * NET + t) * HEADS * DHEAD;
      const float* ar = attn_r + (size_t)(l * NET + t) * HEADS * DHEAD;

      gemm_split<<<MPAD / 64, 256, 0, stream>>>(Ah, Al, Bh, Bl, al, ar, zh, el, er, N_NODES);
      agg_kernel<<<N_NODES / 4, 256, 0, stream>>>(rowptr[t], colA[t], el, er, zh, h,
                                                  b0, b1, b2,
                                                  t == 0, t == NET - 1,
                                                  (t == NET - 1) && (l != LAYERS - 1));
    }
  }
  linear_kernel<<<N_NODES, 256, 0, stream>>>(h, lin_w, lin_b, out);
}

// Round 9
// 1478.853 us; speedup vs baseline: 5.7323x; 1.0706x over previous
//
#include <hip/hip_runtime.h>
#include <hip/hip_bf16.h>
#include <math.h>

#define N_NODES 50000
#define NEDGE 800000
#define NET 3
#define LAYERS 3
#define HEADS 4
#define DHEAD 64
#define NH 256
#define NC 16
#define NEG_SLOPE 0.2f
#define MPAD 50048   // 782 * 64

typedef __attribute__((ext_vector_type(8))) short short8;
typedef __attribute__((ext_vector_type(4))) float f32x4;
typedef __attribute__((ext_vector_type(8))) _Float16 half8;

#define GLDS16(gp, lp) \
  __builtin_amdgcn_global_load_lds((const __attribute__((address_space(1))) void*)(gp), \
                                   (__attribute__((address_space(3))) void*)(lp), 16, 0, 0)

__device__ inline unsigned short f2bf(float x) {
  unsigned u = __float_as_uint(x);
  unsigned r = (u + 0x7FFFu + ((u >> 16) & 1u)) >> 16;
  return (unsigned short)r;
}
__device__ inline float bf2f(unsigned short h) { return __uint_as_float(((unsigned)h) << 16); }

// ---- split W into hi/lo bf16, transposed to [n][k] for MFMA B-operand ----
__global__ void split_transpose_W(const float* __restrict__ W,
                                  unsigned short* __restrict__ WhT,
                                  unsigned short* __restrict__ WlT) {
  int i = blockIdx.x * blockDim.x + threadIdx.x;
  if (i >= LAYERS * NET * NH * NH) return;
  int mat = i >> 16, rem = i & 65535;
  int n = rem >> 8, k = rem & 255;
  float v = W[(size_t)mat * 65536 + k * 256 + n];
  unsigned short hi = f2bf(v);
  unsigned short lo = f2bf(v - bf2f(hi));
  WhT[(size_t)mat * 65536 + n * 256 + k] = hi;
  WlT[(size_t)mat * 65536 + n * 256 + k] = lo;
}

// ---- split activations into hi/lo bf16 (layer 0 only; later layers fused in agg3) ----
__global__ void split_kernel(const float* __restrict__ in, unsigned short* __restrict__ hi,
                             unsigned short* __restrict__ lo) {
  int i = blockIdx.x * blockDim.x + threadIdx.x;
  if (i >= N_NODES * NH / 4) return;
  float4 v = ((const float4*)in)[i];
  ushort4 h, l;
  h.x = f2bf(v.x); l.x = f2bf(v.x - bf2f(h.x));
  h.y = f2bf(v.y); l.y = f2bf(v.y - bf2f(h.y));
  h.z = f2bf(v.z); l.z = f2bf(v.z - bf2f(h.z));
  h.w = f2bf(v.w); l.w = f2bf(v.w - bf2f(h.w));
  ((ushort4*)hi)[i] = h;
  ((ushort4*)lo)[i] = l;
}

// ---- split-bf16 MFMA GEMM: z[M x 256] = A @ W (fp16 out), fused el/er epilogue ----
__global__ __launch_bounds__(256) void gemm_split(const unsigned short* __restrict__ Ah,
                                                  const unsigned short* __restrict__ Al,
                                                  const unsigned short* __restrict__ BhT,
                                                  const unsigned short* __restrict__ BlT,
                                                  const float* __restrict__ al,
                                                  const float* __restrict__ ar,
                                                  _Float16* __restrict__ zh,
                                                  float* __restrict__ el,
                                                  float* __restrict__ er, int M) {
  __shared__ unsigned short lds[20480];  // Ah 64x32 | Al 64x32 | BhT 256x32 | BlT 256x32
  unsigned short* sAh = lds;
  unsigned short* sAl = lds + 2048;
  unsigned short* sBh = lds + 4096;
  unsigned short* sBl = lds + 12288;

  int tid = threadIdx.x;
  int w = tid >> 6, lane = tid & 63;
  int r16 = lane & 15, rk = lane >> 4;
  int bm = blockIdx.x * 64;

  int arow = tid >> 2, acol = (tid & 3) * 8;
  const unsigned short* pAh = Ah + (size_t)(bm + arow) * 256 + acol;
  const unsigned short* pAl = Al + (size_t)(bm + arow) * 256 + acol;

  f32x4 acc[4][4];
#pragma unroll
  for (int m = 0; m < 4; m++)
#pragma unroll
    for (int n = 0; n < 4; n++) acc[m][n] = (f32x4){0.f, 0.f, 0.f, 0.f};

  char* aldsA = (char*)lds + (size_t)w * 1024;

#pragma unroll
  for (int k0 = 0; k0 < 8; k0++) {
    GLDS16(pAh + k0 * 32, aldsA);
    GLDS16(pAl + k0 * 32, (char*)sAl + (size_t)w * 1024);
#pragma unroll
    for (int i = 0; i < 4; i++) {
      int slot = tid + i * 256;
      int nrow = slot >> 2, kcol = (slot & 3) * 8;
      size_t go = (size_t)nrow * 256 + k0 * 32 + kcol;
      char* lb = (char*)sBh + ((size_t)w * 64 + (size_t)i * 256) * 16;
      char* lb2 = (char*)sBl + ((size_t)w * 64 + (size_t)i * 256) * 16;
      GLDS16(BhT + go, lb);
      GLDS16(BlT + go, lb2);
    }
    __syncthreads();

    short8 a_h[4], a_l[4], b_h[4], b_l[4];
#pragma unroll
    for (int m = 0; m < 4; m++) {
      a_h[m] = *(const short8*)&sAh[(m * 16 + r16) * 32 + rk * 8];
      a_l[m] = *(const short8*)&sAl[(m * 16 + r16) * 32 + rk * 8];
    }
#pragma unroll
    for (int n = 0; n < 4; n++) {
      int col = w * 64 + n * 16 + r16;
      b_h[n] = *(const short8*)&sBh[col * 32 + rk * 8];
      b_l[n] = *(const short8*)&sBl[col * 32 + rk * 8];
    }
#pragma unroll
    for (int m = 0; m < 4; m++)
#pragma unroll
      for (int n = 0; n < 4; n++) {
        acc[m][n] = __builtin_amdgcn_mfma_f32_16x16x32_bf16(a_h[m], b_h[n], acc[m][n], 0, 0, 0);
        acc[m][n] = __builtin_amdgcn_mfma_f32_16x16x32_bf16(a_h[m], b_l[n], acc[m][n], 0, 0, 0);
        acc[m][n] = __builtin_amdgcn_mfma_f32_16x16x32_bf16(a_l[m], b_h[n], acc[m][n], 0, 0, 0);
      }
    __syncthreads();
  }

#pragma unroll
  for (int m = 0; m < 4; m++) {
    int row0 = bm + m * 16 + rk * 4;
#pragma unroll
    for (int n = 0; n < 4; n++) {
      int col = w * 64 + n * 16 + r16;
#pragma unroll
      for (int r = 0; r < 4; r++) {
        int row = row0 + r;
        if (row < M) zh[(size_t)row * 256 + col] = (_Float16)acc[m][n][r];
      }
    }
  }

  float alv[4], arv[4];
#pragma unroll
  for (int n = 0; n < 4; n++) {
    alv[n] = al[w * 64 + n * 16 + r16];
    arv[n] = ar[w * 64 + n * 16 + r16];
  }
#pragma unroll
  for (int m = 0; m < 4; m++) {
#pragma unroll
    for (int r = 0; r < 4; r++) {
      float pl = 0.f, pr = 0.f;
#pragma unroll
      for (int n = 0; n < 4; n++) {
        float zv = acc[m][n][r];
        pl = fmaf(zv, alv[n], pl);
        pr = fmaf(zv, arv[n], pr);
      }
      pl += __shfl_xor(pl, 1, 64); pl += __shfl_xor(pl, 2, 64);
      pl += __shfl_xor(pl, 4, 64); pl += __shfl_xor(pl, 8, 64);
      pr += __shfl_xor(pr, 1, 64); pr += __shfl_xor(pr, 2, 64);
      pr += __shfl_xor(pr, 4, 64); pr += __shfl_xor(pr, 8, 64);
      int row = bm + m * 16 + rk * 4 + r;
      if (r16 == 0 && row < M) {
        el[row * HEADS + w] = pl;
        er[row * HEADS + w] = pr;
      }
    }
  }
}

__device__ inline float leaky(float v) { return v > 0.f ? v : NEG_SLOPE * v; }

// ---------------- CSR build ----------------
__global__ void deg_kernel(const int* __restrict__ dst, int* __restrict__ deg) {
  int e = blockIdx.x * blockDim.x + threadIdx.x;
  if (e < NEDGE) atomicAdd(&deg[dst[e]], 1);
}

__global__ __launch_bounds__(1024) void scan_kernel(const int* __restrict__ deg,
                                                    int* __restrict__ rowptr) {
  __shared__ int wsum[16];
  __shared__ int carry_s;
  int tid = threadIdx.x;
  int lane = tid & 63, wv = tid >> 6;
  if (tid == 0) { carry_s = 0; rowptr[0] = 0; }
  __syncthreads();
  for (int base = 0; base < N_NODES; base += 1024) {
    int i = base + tid;
    int v = (i < N_NODES) ? deg[i] : 0;
    int x = v;
#pragma unroll
    for (int off = 1; off < 64; off <<= 1) {
      int y = __shfl_up(x, off, 64);
      if (lane >= off) x += y;
    }
    if (lane == 63) wsum[wv] = x;
    __syncthreads();
    if (wv == 0 && lane < 16) {
      int s = wsum[lane];
#pragma unroll
      for (int off = 1; off < 16; off <<= 1) {
        int y = __shfl_up(s, off, 16);
        if (lane >= off) s += y;
      }
      wsum[lane] = s;
    }
    __syncthreads();
    int waveoff = (wv > 0) ? wsum[wv - 1] : 0;
    int incl = x + waveoff + carry_s;
    if (i < N_NODES) rowptr[i + 1] = incl;
    __syncthreads();
    if (tid == 1023) carry_s = incl;
    __syncthreads();
  }
}

// store global z-row index (t*N + src) so fused agg can address fused buffers
__global__ void scatter_kernel(const int* __restrict__ src, const int* __restrict__ dst,
                               int* __restrict__ cursor, int* __restrict__ col, int rowoff) {
  int e = blockIdx.x * blockDim.x + threadIdx.x;
  if (e < NEDGE) {
    int d = dst[e];
    int pos = atomicAdd(&cursor[d], 1);
    col[pos] = src[e] + rowoff;
  }
}

// ---------------- fused 3-etype softmax + aggregation + split epilogue ----------------
// one wave per dst node; loops etypes, per-etype softmax (exact), reg accumulation.
// Phase A: lane=(edge kk=lane&15, head hh=lane>>4) scores 16 edges/iter -> LDS.
// Phase B: halves (which=lane>>5) gather z rows, 2x unrolled (4 rows in flight).
__global__ __launch_bounds__(256) void agg3_kernel(const int* __restrict__ rowptr,  // [3][N+1]
                                                   const int* __restrict__ col,     // [3][E]
                                                   const float* __restrict__ el,    // [3N][4]
                                                   const float* __restrict__ er,    // [3N][4]
                                                   const _Float16* __restrict__ zh, // [3N][256]
                                                   float* __restrict__ hout,
                                                   unsigned short* __restrict__ Ah,
                                                   unsigned short* __restrict__ Al,
                                                   const float* __restrict__ b0,
                                                   const float* __restrict__ b1,
                                                   const float* __restrict__ b2,
                                                   int final_layer) {
  __shared__ float s_alpha[4][128][4];
  __shared__ int s_col[4][128];

  int wv = threadIdx.x >> 6, lane = threadIdx.x & 63;
  int n = blockIdx.x * 4 + wv;
  int kk = lane & 15, hh = lane >> 4;
  int which = lane >> 5, lj = lane & 31, fh = lj >> 3;

  float v0 = 0.f, v1 = 0.f, v2 = 0.f, v3 = 0.f;
  float v4 = 0.f, v5 = 0.f, v6 = 0.f, v7 = 0.f;

  for (int t = 0; t < NET; t++) {
    int rs = rowptr[t * (N_NODES + 1) + n];
    int deg = rowptr[t * (N_NODES + 1) + n + 1] - rs;
    const int* colt = col + (size_t)t * NEDGE;
    float erh = er[((size_t)t * N_NODES + n) * HEADS + hh];

    float sm = 0.f;
    float a0 = 0.f, a1 = 0.f, a2 = 0.f, a3 = 0.f;
    float a4 = 0.f, a5 = 0.f, a6 = 0.f, a7 = 0.f;

    for (int s0 = 0; s0 < deg; s0 += 128) {
      int segN = min(128, deg - s0);
      // phase A
      for (int c0 = 0; c0 < segN; c0 += 16) {
        if (c0 + kk < segN) {
          int row = colt[rs + s0 + c0 + kk];
          float a = __expf(leaky(el[(size_t)row * HEADS + hh] + erh));
          sm += a;
          s_alpha[wv][c0 + kk][hh] = a;
          if (hh == 0) s_col[wv][c0 + kk] = row;
        }
      }
      // phase B (2x unrolled: 4 rows in flight per wave)
      int k = which;
      for (; k + 2 < segN; k += 4) {
        float aa = s_alpha[wv][k][fh];     int ra = s_col[wv][k];
        float ab = s_alpha[wv][k + 2][fh]; int rb = s_col[wv][k + 2];
        half8 va = *(const half8*)&zh[(size_t)ra * NH + lj * 8];
        half8 vb = *(const half8*)&zh[(size_t)rb * NH + lj * 8];
        a0 = fmaf(aa, (float)va[0], a0); a1 = fmaf(aa, (float)va[1], a1);
        a2 = fmaf(aa, (float)va[2], a2); a3 = fmaf(aa, (float)va[3], a3);
        a4 = fmaf(aa, (float)va[4], a4); a5 = fmaf(aa, (float)va[5], a5);
        a6 = fmaf(aa, (float)va[6], a6); a7 = fmaf(aa, (float)va[7], a7);
        a0 = fmaf(ab, (float)vb[0], a0); a1 = fmaf(ab, (float)vb[1], a1);
        a2 = fmaf(ab, (float)vb[2], a2); a3 = fmaf(ab, (float)vb[3], a3);
        a4 = fmaf(ab, (float)vb[4], a4); a5 = fmaf(ab, (float)vb[5], a5);
        a6 = fmaf(ab, (float)vb[6], a6); a7 = fmaf(ab, (float)vb[7], a7);
      }
      for (; k < segN; k += 2) {
        float aa = s_alpha[wv][k][fh];
        int ra = s_col[wv][k];
        half8 va = *(const half8*)&zh[(size_t)ra * NH + lj * 8];
        a0 = fmaf(aa, (float)va[0], a0); a1 = fmaf(aa, (float)va[1], a1);
        a2 = fmaf(aa, (float)va[2], a2); a3 = fmaf(aa, (float)va[3], a3);
        a4 = fmaf(aa, (float)va[4], a4); a5 = fmaf(aa, (float)va[5], a5);
        a6 = fmaf(aa, (float)va[6], a6); a7 = fmaf(aa, (float)va[7], a7);
      }
    }

    // per-etype denom (phase-A layout), broadcast to phase-B layout
    sm += __shfl_xor(sm, 1, 64);
    sm += __shfl_xor(sm, 2, 64);
    sm += __shfl_xor(sm, 4, 64);
    sm += __shfl_xor(sm, 8, 64);
    float inv = (deg > 0) ? 1.f / sm : 0.f;
    float invb = __shfl(inv, fh * 16, 64);

    // merge halves (both halves end with full sum)
    a0 += __shfl_xor(a0, 32, 64); a1 += __shfl_xor(a1, 32, 64);
    a2 += __shfl_xor(a2, 32, 64); a3 += __shfl_xor(a3, 32, 64);
    a4 += __shfl_xor(a4, 32, 64); a5 += __shfl_xor(a5, 32, 64);
    a6 += __shfl_xor(a6, 32, 64); a7 += __shfl_xor(a7, 32, 64);

    v0 = fmaf(a0, invb, v0); v1 = fmaf(a1, invb, v1);
    v2 = fmaf(a2, invb, v2); v3 = fmaf(a3, invb, v3);
    v4 = fmaf(a4, invb, v4); v5 = fmaf(a5, invb, v5);
    v6 = fmaf(a6, invb, v6); v7 = fmaf(a7, invb, v7);
  }

  if (lane < 32) {
    int f0 = lj * 8;
    float vo[8] = {v0, v1, v2, v3, v4, v5, v6, v7};
#pragma unroll
    for (int i = 0; i < 8; i++) vo[i] += b0[f0 + i] + b1[f0 + i] + b2[f0 + i];
    if (final_layer) {
      size_t oi = (size_t)n * NH + f0;
      float4 o0 = {vo[0], vo[1], vo[2], vo[3]};
      float4 o1 = {vo[4], vo[5], vo[6], vo[7]};
      *(float4*)&hout[oi] = o0;
      *(float4*)&hout[oi + 4] = o1;
    } else {
      ushort4 hi0, hi1, lo0, lo1;
#pragma unroll
      for (int i = 0; i < 8; i++) vo[i] = fmaxf(vo[i], 0.f);  // relu
      hi0.x = f2bf(vo[0]); lo0.x = f2bf(vo[0] - bf2f(hi0.x));
      hi0.y = f2bf(vo[1]); lo0.y = f2bf(vo[1] - bf2f(hi0.y));
      hi0.z = f2bf(vo[2]); lo0.z = f2bf(vo[2] - bf2f(hi0.z));
      hi0.w = f2bf(vo[3]); lo0.w = f2bf(vo[3] - bf2f(hi0.w));
      hi1.x = f2bf(vo[4]); lo1.x = f2bf(vo[4] - bf2f(hi1.x));
      hi1.y = f2bf(vo[5]); lo1.y = f2bf(vo[5] - bf2f(hi1.y));
      hi1.z = f2bf(vo[6]); lo1.z = f2bf(vo[6] - bf2f(hi1.z));
      hi1.w = f2bf(vo[7]); lo1.w = f2bf(vo[7] - bf2f(hi1.w));
      size_t oi = (size_t)n * NH + f0;
      *(ushort4*)&Ah[oi] = hi0;
      *(ushort4*)&Ah[oi + 4] = hi1;
      *(ushort4*)&Al[oi] = lo0;
      *(ushort4*)&Al[oi + 4] = lo1;
    }
  }
}

__global__ __launch_bounds__(256) void linear_kernel(const float* __restrict__ h,
                                                     const float* __restrict__ w,
                                                     const float* __restrict__ b,
                                                     float* __restrict__ out) {
  __shared__ float part[16][17];
  int n = blockIdx.x;
  int t = threadIdx.x;
  int c = t & 15, p = t >> 4;
  float sum = 0.f;
#pragma unroll
  for (int q = 0; q < 16; q++) {
    int j = p * 16 + q;
    sum = fmaf(h[(size_t)n * NH + j], w[j * NC + c], sum);
  }
  part[p][c] = sum;
  __syncthreads();
  if (t < 16) {
    float s = 0.f;
#pragma unroll
    for (int p2 = 0; p2 < 16; p2++) s += part[p2][t];
    out[n * NC + t] = s + b[t];
  }
}

extern "C" void kernel_launch(void* const* d_in, const int* in_sizes, int n_in,
                              void* d_out, int out_size, void* d_ws, size_t ws_size,
                              hipStream_t stream) {
  const float* x      = (const float*)d_in[0];
  const int*   src    = (const int*)d_in[1];
  const int*   dst    = (const int*)d_in[2];
  const float* W      = (const float*)d_in[3];
  const float* attn_l = (const float*)d_in[4];
  const float* attn_r = (const float*)d_in[5];
  const float* bias   = (const float*)d_in[6];
  const float* lin_w  = (const float*)d_in[7];
  const float* lin_b  = (const float*)d_in[8];
  float* out = (float*)d_out;

  char* ws = (char*)d_ws;
  size_t off = 0;
  _Float16* zh = (_Float16*)(ws + off); off += (size_t)NET * N_NODES * NH * 2;   // 76.8 MB
  unsigned short* Ah = (unsigned short*)(ws + off); off += (size_t)MPAD * NH * 2; // 25.6 MB
  unsigned short* Al = (unsigned short*)(ws + off); off += (size_t)MPAD * NH * 2; // 25.6 MB
  float* h = (float*)Ah;  // aliases Ah+Al (dead by the time h is written in the final layer)
  unsigned short* WhT = (unsigned short*)(ws + off); off += (size_t)LAYERS * NET * NH * NH * 2;
  unsigned short* WlT = (unsigned short*)(ws + off); off += (size_t)LAYERS * NET * NH * NH * 2;
  float* el = (float*)(ws + off); off += (size_t)NET * N_NODES * HEADS * 4;
  float* er = (float*)(ws + off); off += (size_t)NET * N_NODES * HEADS * 4;
  int* rowptr = (int*)(ws + off); off += (size_t)NET * (N_NODES + 1) * 4;
  int* colA   = (int*)(ws + off); off += (size_t)NET * NEDGE * 4;
  int* deg    = (int*)(ws + off); off += (size_t)N_NODES * 4;
  int* cursor = (int*)(ws + off); off += (size_t)N_NODES * 4;

  // ---- build dst-CSR per etype (graph is call-invariant) ----
  for (int t = 0; t < NET; t++) {
    const int* d_t = dst + (size_t)t * NEDGE;
    const int* s_t = src + (size_t)t * NEDGE;
    int* rp_t = rowptr + (size_t)t * (N_NODES + 1);
    hipMemsetAsync(deg, 0, (size_t)N_NODES * 4, stream);
    deg_kernel<<<(NEDGE + 255) / 256, 256, 0, stream>>>(d_t, deg);
    scan_kernel<<<1, 1024, 0, stream>>>(deg, rp_t);
    hipMemcpyAsync(cursor, rp_t, (size_t)N_NODES * 4, hipMemcpyDeviceToDevice, stream);
    scatter_kernel<<<(NEDGE + 255) / 256, 256, 0, stream>>>(s_t, d_t, cursor,
                                                            colA + (size_t)t * NEDGE,
                                                            t * N_NODES);
  }

  // ---- split + transpose all weights once ----
  split_transpose_W<<<(LAYERS * NET * NH * NH + 255) / 256, 256, 0, stream>>>(W, WhT, WlT);

  // ---- layer 0 input split (later layers produce Ah/Al in agg3 epilogue) ----
  split_kernel<<<(N_NODES * NH / 4 + 255) / 256, 256, 0, stream>>>(x, Ah, Al);

  for (int l = 0; l < LAYERS; l++) {
    const float* b0 = bias + (size_t)(l * NET + 0) * NH;
    const float* b1 = bias + (size_t)(l * NET + 1) * NH;
    const float* b2 = bias + (size_t)(l * NET + 2) * NH;

    for (int t = 0; t < NET; t++) {
      const unsigned short* Bh = WhT + (size_t)(l * NET + t) * NH * NH;
      const unsigned short* Bl = WlT + (size_t)(l * NET + t) * NH * NH;
      const float* al = attn_l + (size_t)(l * NET + t) * HEADS * DHEAD;
      const float* ar = attn_r + (size_t)(l * NET + t) * HEADS * DHEAD;
      gemm_split<<<MPAD / 64, 256, 0, stream>>>(Ah, Al, Bh, Bl, al, ar,
                                                zh + (size_t)t * N_NODES * NH,
                                                el + (size_t)t * N_NODES * HEADS,
                                                er + (size_t)t * N_NODES * HEADS, N_NODES);
    }
    agg3_kernel<<<N_NODES / 4, 256, 0, stream>>>(rowptr, colA, el, er, zh, h, Ah, Al,
                                                 b0, b1, b2, l == LAYERS - 1);
  }
  linear_kernel<<<N_NODES, 256, 0, stream>>>(h, lin_w, lin_b, out);
}

// Round 10
// 1315.217 us; speedup vs baseline: 6.4455x; 1.1244x over previous
//
#include <hip/hip_runtime.h>
#include <hip/hip_bf16.h>
#include <math.h>

#define N_NODES 50000
#define NEDGE 800000
#define NET 3
#define LAYERS 3
#define HEADS 4
#define DHEAD 64
#define NH 256
#define NC 16
#define NEG_SLOPE 0.2f
#define MPAD 50048   // 782 * 64
#define NTOT (NET * N_NODES)          // 150000 virtual dst nodes
#define SCAN_BLOCKS ((NTOT + 1023) / 1024)  // 147

typedef __attribute__((ext_vector_type(8))) short short8;
typedef __attribute__((ext_vector_type(4))) float f32x4;
typedef __attribute__((ext_vector_type(8))) _Float16 half8;

#define GLDS16(gp, lp) \
  __builtin_amdgcn_global_load_lds((const __attribute__((address_space(1))) void*)(gp), \
                                   (__attribute__((address_space(3))) void*)(lp), 16, 0, 0)

__device__ inline unsigned short f2bf(float x) {
  unsigned u = __float_as_uint(x);
  unsigned r = (u + 0x7FFFu + ((u >> 16) & 1u)) >> 16;
  return (unsigned short)r;
}
__device__ inline float bf2f(unsigned short h) { return __uint_as_float(((unsigned)h) << 16); }

// ---- split W into hi/lo bf16, transposed to [n][k] for MFMA B-operand ----
__global__ void split_transpose_W(const float* __restrict__ W,
                                  unsigned short* __restrict__ WhT,
                                  unsigned short* __restrict__ WlT) {
  int i = blockIdx.x * blockDim.x + threadIdx.x;
  if (i >= LAYERS * NET * NH * NH) return;
  int mat = i >> 16, rem = i & 65535;
  int n = rem >> 8, k = rem & 255;
  float v = W[(size_t)mat * 65536 + k * 256 + n];
  unsigned short hi = f2bf(v);
  unsigned short lo = f2bf(v - bf2f(hi));
  WhT[(size_t)mat * 65536 + n * 256 + k] = hi;
  WlT[(size_t)mat * 65536 + n * 256 + k] = lo;
}

// ---- split activations into hi/lo bf16 (layer 0 only; later layers fused in agg3) ----
__global__ void split_kernel(const float* __restrict__ in, unsigned short* __restrict__ hi,
                             unsigned short* __restrict__ lo) {
  int i = blockIdx.x * blockDim.x + threadIdx.x;
  if (i >= N_NODES * NH / 4) return;
  float4 v = ((const float4*)in)[i];
  ushort4 h, l;
  h.x = f2bf(v.x); l.x = f2bf(v.x - bf2f(h.x));
  h.y = f2bf(v.y); l.y = f2bf(v.y - bf2f(h.y));
  h.z = f2bf(v.z); l.z = f2bf(v.z - bf2f(h.z));
  h.w = f2bf(v.w); l.w = f2bf(v.w - bf2f(h.w));
  ((ushort4*)hi)[i] = h;
  ((ushort4*)lo)[i] = l;
}

// ---- split-bf16 MFMA GEMM for all 3 etypes (blockIdx.y = t), fused el/er epilogue ----
__global__ __launch_bounds__(256) void gemm_split3(const unsigned short* __restrict__ Ah,
                                                   const unsigned short* __restrict__ Al,
                                                   const unsigned short* __restrict__ WhT_l,
                                                   const unsigned short* __restrict__ WlT_l,
                                                   const float* __restrict__ attn_l_l,
                                                   const float* __restrict__ attn_r_l,
                                                   _Float16* __restrict__ zh_all,
                                                   float* __restrict__ el_all,
                                                   float* __restrict__ er_all, int M) {
  int t = blockIdx.y;
  const unsigned short* BhT = WhT_l + (size_t)t * NH * NH;
  const unsigned short* BlT = WlT_l + (size_t)t * NH * NH;
  const float* al = attn_l_l + (size_t)t * NH;
  const float* ar = attn_r_l + (size_t)t * NH;
  _Float16* zh = zh_all + (size_t)t * N_NODES * NH;
  float* el = el_all + (size_t)t * N_NODES * HEADS;
  float* er = er_all + (size_t)t * N_NODES * HEADS;

  __shared__ unsigned short lds[20480];  // Ah 64x32 | Al 64x32 | BhT 256x32 | BlT 256x32
  unsigned short* sAh = lds;
  unsigned short* sAl = lds + 2048;
  unsigned short* sBh = lds + 4096;
  unsigned short* sBl = lds + 12288;

  int tid = threadIdx.x;
  int w = tid >> 6, lane = tid & 63;
  int r16 = lane & 15, rk = lane >> 4;
  int bm = blockIdx.x * 64;

  int arow = tid >> 2, acol = (tid & 3) * 8;
  const unsigned short* pAh = Ah + (size_t)(bm + arow) * 256 + acol;
  const unsigned short* pAl = Al + (size_t)(bm + arow) * 256 + acol;

  f32x4 acc[4][4];
#pragma unroll
  for (int m = 0; m < 4; m++)
#pragma unroll
    for (int n = 0; n < 4; n++) acc[m][n] = (f32x4){0.f, 0.f, 0.f, 0.f};

  char* aldsA = (char*)lds + (size_t)w * 1024;

#pragma unroll
  for (int k0 = 0; k0 < 8; k0++) {
    GLDS16(pAh + k0 * 32, aldsA);
    GLDS16(pAl + k0 * 32, (char*)sAl + (size_t)w * 1024);
#pragma unroll
    for (int i = 0; i < 4; i++) {
      int slot = tid + i * 256;
      int nrow = slot >> 2, kcol = (slot & 3) * 8;
      size_t go = (size_t)nrow * 256 + k0 * 32 + kcol;
      char* lb = (char*)sBh + ((size_t)w * 64 + (size_t)i * 256) * 16;
      char* lb2 = (char*)sBl + ((size_t)w * 64 + (size_t)i * 256) * 16;
      GLDS16(BhT + go, lb);
      GLDS16(BlT + go, lb2);
    }
    __syncthreads();

    short8 a_h[4], a_l[4], b_h[4], b_l[4];
#pragma unroll
    for (int m = 0; m < 4; m++) {
      a_h[m] = *(const short8*)&sAh[(m * 16 + r16) * 32 + rk * 8];
      a_l[m] = *(const short8*)&sAl[(m * 16 + r16) * 32 + rk * 8];
    }
#pragma unroll
    for (int n = 0; n < 4; n++) {
      int col = w * 64 + n * 16 + r16;
      b_h[n] = *(const short8*)&sBh[col * 32 + rk * 8];
      b_l[n] = *(const short8*)&sBl[col * 32 + rk * 8];
    }
#pragma unroll
    for (int m = 0; m < 4; m++)
#pragma unroll
      for (int n = 0; n < 4; n++) {
        acc[m][n] = __builtin_amdgcn_mfma_f32_16x16x32_bf16(a_h[m], b_h[n], acc[m][n], 0, 0, 0);
        acc[m][n] = __builtin_amdgcn_mfma_f32_16x16x32_bf16(a_h[m], b_l[n], acc[m][n], 0, 0, 0);
        acc[m][n] = __builtin_amdgcn_mfma_f32_16x16x32_bf16(a_l[m], b_h[n], acc[m][n], 0, 0, 0);
      }
    __syncthreads();
  }

#pragma unroll
  for (int m = 0; m < 4; m++) {
    int row0 = bm + m * 16 + rk * 4;
#pragma unroll
    for (int n = 0; n < 4; n++) {
      int col = w * 64 + n * 16 + r16;
#pragma unroll
      for (int r = 0; r < 4; r++) {
        int row = row0 + r;
        if (row < M) zh[(size_t)row * 256 + col] = (_Float16)acc[m][n][r];
      }
    }
  }

  float alv[4], arv[4];
#pragma unroll
  for (int n = 0; n < 4; n++) {
    alv[n] = al[w * 64 + n * 16 + r16];
    arv[n] = ar[w * 64 + n * 16 + r16];
  }
#pragma unroll
  for (int m = 0; m < 4; m++) {
#pragma unroll
    for (int r = 0; r < 4; r++) {
      float pl = 0.f, pr = 0.f;
#pragma unroll
      for (int n = 0; n < 4; n++) {
        float zv = acc[m][n][r];
        pl = fmaf(zv, alv[n], pl);
        pr = fmaf(zv, arv[n], pr);
      }
      pl += __shfl_xor(pl, 1, 64); pl += __shfl_xor(pl, 2, 64);
      pl += __shfl_xor(pl, 4, 64); pl += __shfl_xor(pl, 8, 64);
      pr += __shfl_xor(pr, 1, 64); pr += __shfl_xor(pr, 2, 64);
      pr += __shfl_xor(pr, 4, 64); pr += __shfl_xor(pr, 8, 64);
      int row = bm + m * 16 + rk * 4 + r;
      if (r16 == 0 && row < M) {
        el[row * HEADS + w] = pl;
        er[row * HEADS + w] = pr;
      }
    }
  }
}

__device__ inline float leaky(float v) { return v > 0.f ? v : NEG_SLOPE * v; }

// ---------------- global CSR build over 3N virtual dst nodes ----------------
__global__ void deg_kernel(const int* __restrict__ dst, int* __restrict__ deg) {
  int e = blockIdx.x * blockDim.x + threadIdx.x;
  int t = blockIdx.y;
  atomicAdd(&deg[t * N_NODES + dst[(size_t)t * NEDGE + e]], 1);
}

// hierarchical scan: block-local inclusive scan + block sums
__global__ __launch_bounds__(1024) void scan1_kernel(const int* __restrict__ deg,
                                                     int* __restrict__ incl,
                                                     int* __restrict__ bsum) {
  __shared__ int wsum[16];
  int tid = threadIdx.x;
  int gid = blockIdx.x * 1024 + tid;
  int lane = tid & 63, wv = tid >> 6;
  int v = (gid < NTOT) ? deg[gid] : 0;
  int x = v;
#pragma unroll
  for (int off = 1; off < 64; off <<= 1) {
    int y = __shfl_up(x, off, 64);
    if (lane >= off) x += y;
  }
  if (lane == 63) wsum[wv] = x;
  __syncthreads();
  if (wv == 0 && lane < 16) {
    int s = wsum[lane];
#pragma unroll
    for (int off = 1; off < 16; off <<= 1) {
      int y = __shfl_up(s, off, 16);
      if (lane >= off) s += y;
    }
    wsum[lane] = s;
  }
  __syncthreads();
  int waveoff = (wv > 0) ? wsum[wv - 1] : 0;
  int inclv = x + waveoff;
  if (gid < NTOT) incl[gid] = inclv;
  if (tid == 1023) bsum[blockIdx.x] = inclv;
}

// exclusive scan of the (<=256) block sums, in place
__global__ __launch_bounds__(256) void scan2_kernel(int* __restrict__ bsum, int nb) {
  __shared__ int wsum[4];
  int tid = threadIdx.x;
  int lane = tid & 63, wv = tid >> 6;
  int v = (tid < nb) ? bsum[tid] : 0;
  int x = v;
#pragma unroll
  for (int off = 1; off < 64; off <<= 1) {
    int y = __shfl_up(x, off, 64);
    if (lane >= off) x += y;
  }
  if (lane == 63) wsum[wv] = x;
  __syncthreads();
  if (wv == 0 && lane < 4) {
    int s = wsum[lane];
#pragma unroll
    for (int off = 1; off < 4; off <<= 1) {
      int y = __shfl_up(s, off, 4);
      if (lane >= off) s += y;
    }
    wsum[lane] = s;
  }
  __syncthreads();
  int waveoff = (wv > 0) ? wsum[wv - 1] : 0;
  if (tid < nb) bsum[tid] = x + waveoff - v;  // exclusive
}

__global__ __launch_bounds__(1024) void scan3_kernel(const int* __restrict__ incl,
                                                     const int* __restrict__ bsum,
                                                     int* __restrict__ rowptr) {
  int tid = threadIdx.x;
  int gid = blockIdx.x * 1024 + tid;
  if (gid < NTOT) rowptr[gid + 1] = incl[gid] + bsum[blockIdx.x];
  if (gid == 0) rowptr[0] = 0;
}

// col[pos] = global z-row index (t*N + src)
__global__ void scatter_kernel(const int* __restrict__ src, const int* __restrict__ dst,
                               int* __restrict__ cursor, int* __restrict__ col) {
  int e = blockIdx.x * blockDim.x + threadIdx.x;
  int t = blockIdx.y;
  int d = dst[(size_t)t * NEDGE + e];
  int pos = atomicAdd(&cursor[t * N_NODES + d], 1);
  col[pos] = src[(size_t)t * NEDGE + e] + t * N_NODES;
}

// ---------------- fused 3-etype softmax + aggregation + split epilogue ----------------
__global__ __launch_bounds__(256) void agg3_kernel(const int* __restrict__ rowptr,  // [3N+1]
                                                   const int* __restrict__ col,     // [3E] global
                                                   const float* __restrict__ el,    // [3N][4]
                                                   const float* __restrict__ er,    // [3N][4]
                                                   const _Float16* __restrict__ zh, // [3N][256]
                                                   float* __restrict__ hout,
                                                   unsigned short* __restrict__ Ah,
                                                   unsigned short* __restrict__ Al,
                                                   const float* __restrict__ b0,
                                                   const float* __restrict__ b1,
                                                   const float* __restrict__ b2,
                                                   int final_layer) {
  __shared__ float s_alpha[4][128][4];
  __shared__ int s_col[4][128];

  int wv = threadIdx.x >> 6, lane = threadIdx.x & 63;
  int n = blockIdx.x * 4 + wv;
  int kk = lane & 15, hh = lane >> 4;
  int which = lane >> 5, lj = lane & 31, fh = lj >> 3;

  float v0 = 0.f, v1 = 0.f, v2 = 0.f, v3 = 0.f;
  float v4 = 0.f, v5 = 0.f, v6 = 0.f, v7 = 0.f;

  for (int t = 0; t < NET; t++) {
    int gn = t * N_NODES + n;
    int rs = rowptr[gn];
    int deg = rowptr[gn + 1] - rs;
    float erh = er[(size_t)gn * HEADS + hh];

    float sm = 0.f;
    float a0 = 0.f, a1 = 0.f, a2 = 0.f, a3 = 0.f;
    float a4 = 0.f, a5 = 0.f, a6 = 0.f, a7 = 0.f;

    for (int s0 = 0; s0 < deg; s0 += 128) {
      int segN = min(128, deg - s0);
      // phase A: 16 edges x 4 heads per iteration
      for (int c0 = 0; c0 < segN; c0 += 16) {
        if (c0 + kk < segN) {
          int row = col[rs + s0 + c0 + kk];
          float a = __expf(leaky(el[(size_t)row * HEADS + hh] + erh));
          sm += a;
          s_alpha[wv][c0 + kk][hh] = a;
          if (hh == 0) s_col[wv][c0 + kk] = row;
        }
      }
      // phase B: x4 unrolled => 8 z rows in flight per wave
      int k = which;
      for (; k + 6 < segN; k += 8) {
        float aa = s_alpha[wv][k][fh];     int ra = s_col[wv][k];
        float ab = s_alpha[wv][k + 2][fh]; int rb = s_col[wv][k + 2];
        float ac = s_alpha[wv][k + 4][fh]; int rc = s_col[wv][k + 4];
        float ad = s_alpha[wv][k + 6][fh]; int rd = s_col[wv][k + 6];
        half8 va = *(const half8*)&zh[(size_t)ra * NH + lj * 8];
        half8 vb = *(const half8*)&zh[(size_t)rb * NH + lj * 8];
        half8 vc = *(const half8*)&zh[(size_t)rc * NH + lj * 8];
        half8 vd = *(const half8*)&zh[(size_t)rd * NH + lj * 8];
        a0 = fmaf(aa, (float)va[0], a0); a1 = fmaf(aa, (float)va[1], a1);
        a2 = fmaf(aa, (float)va[2], a2); a3 = fmaf(aa, (float)va[3], a3);
        a4 = fmaf(aa, (float)va[4], a4); a5 = fmaf(aa, (float)va[5], a5);
        a6 = fmaf(aa, (float)va[6], a6); a7 = fmaf(aa, (float)va[7], a7);
        a0 = fmaf(ab, (float)vb[0], a0); a1 = fmaf(ab, (float)vb[1], a1);
        a2 = fmaf(ab, (float)vb[2], a2); a3 = fmaf(ab, (float)vb[3], a3);
        a4 = fmaf(ab, (float)vb[4], a4); a5 = fmaf(ab, (float)vb[5], a5);
        a6 = fmaf(ab, (float)vb[6], a6); a7 = fmaf(ab, (float)vb[7], a7);
        a0 = fmaf(ac, (float)vc[0], a0); a1 = fmaf(ac, (float)vc[1], a1);
        a2 = fmaf(ac, (float)vc[2], a2); a3 = fmaf(ac, (float)vc[3], a3);
        a4 = fmaf(ac, (float)vc[4], a4); a5 = fmaf(ac, (float)vc[5], a5);
        a6 = fmaf(ac, (float)vc[6], a6); a7 = fmaf(ac, (float)vc[7], a7);
        a0 = fmaf(ad, (float)vd[0], a0); a1 = fmaf(ad, (float)vd[1], a1);
        a2 = fmaf(ad, (float)vd[2], a2); a3 = fmaf(ad, (float)vd[3], a3);
        a4 = fmaf(ad, (float)vd[4], a4); a5 = fmaf(ad, (float)vd[5], a5);
        a6 = fmaf(ad, (float)vd[6], a6); a7 = fmaf(ad, (float)vd[7], a7);
      }
      for (; k < segN; k += 2) {
        float aa = s_alpha[wv][k][fh];
        int ra = s_col[wv][k];
        half8 va = *(const half8*)&zh[(size_t)ra * NH + lj * 8];
        a0 = fmaf(aa, (float)va[0], a0); a1 = fmaf(aa, (float)va[1], a1);
        a2 = fmaf(aa, (float)va[2], a2); a3 = fmaf(aa, (float)va[3], a3);
        a4 = fmaf(aa, (float)va[4], a4); a5 = fmaf(aa, (float)va[5], a5);
        a6 = fmaf(aa, (float)va[6], a6); a7 = fmaf(aa, (float)va[7], a7);
      }
    }

    // per-etype denom (phase-A layout), broadcast to phase-B layout
    sm += __shfl_xor(sm, 1, 64);
    sm += __shfl_xor(sm, 2, 64);
    sm += __shfl_xor(sm, 4, 64);
    sm += __shfl_xor(sm, 8, 64);
    float inv = (deg > 0) ? 1.f / sm : 0.f;
    float invb = __shfl(inv, fh * 16, 64);

    // merge halves
    a0 += __shfl_xor(a0, 32, 64); a1 += __shfl_xor(a1, 32, 64);
    a2 += __shfl_xor(a2, 32, 64); a3 += __shfl_xor(a3, 32, 64);
    a4 += __shfl_xor(a4, 32, 64); a5 += __shfl_xor(a5, 32, 64);
    a6 += __shfl_xor(a6, 32, 64); a7 += __shfl_xor(a7, 32, 64);

    v0 = fmaf(a0, invb, v0); v1 = fmaf(a1, invb, v1);
    v2 = fmaf(a2, invb, v2); v3 = fmaf(a3, invb, v3);
    v4 = fmaf(a4, invb, v4); v5 = fmaf(a5, invb, v5);
    v6 = fmaf(a6, invb, v6); v7 = fmaf(a7, invb, v7);
  }

  if (lane < 32) {
    int f0 = lj * 8;
    float vo[8] = {v0, v1, v2, v3, v4, v5, v6, v7};
#pragma unroll
    for (int i = 0; i < 8; i++) vo[i] += b0[f0 + i] + b1[f0 + i] + b2[f0 + i];
    if (final_layer) {
      size_t oi = (size_t)n * NH + f0;
      float4 o0 = {vo[0], vo[1], vo[2], vo[3]};
      float4 o1 = {vo[4], vo[5], vo[6], vo[7]};
      *(float4*)&hout[oi] = o0;
      *(float4*)&hout[oi + 4] = o1;
    } else {
      ushort4 hi0, hi1, lo0, lo1;
#pragma unroll
      for (int i = 0; i < 8; i++) vo[i] = fmaxf(vo[i], 0.f);  // relu
      hi0.x = f2bf(vo[0]); lo0.x = f2bf(vo[0] - bf2f(hi0.x));
      hi0.y = f2bf(vo[1]); lo0.y = f2bf(vo[1] - bf2f(hi0.y));
      hi0.z = f2bf(vo[2]); lo0.z = f2bf(vo[2] - bf2f(hi0.z));
      hi0.w = f2bf(vo[3]); lo0.w = f2bf(vo[3] - bf2f(hi0.w));
      hi1.x = f2bf(vo[4]); lo1.x = f2bf(vo[4] - bf2f(hi1.x));
      hi1.y = f2bf(vo[5]); lo1.y = f2bf(vo[5] - bf2f(hi1.y));
      hi1.z = f2bf(vo[6]); lo1.z = f2bf(vo[6] - bf2f(hi1.z));
      hi1.w = f2bf(vo[7]); lo1.w = f2bf(vo[7] - bf2f(hi1.w));
      size_t oi = (size_t)n * NH + f0;
      *(ushort4*)&Ah[oi] = hi0;
      *(ushort4*)&Ah[oi + 4] = hi1;
      *(ushort4*)&Al[oi] = lo0;
      *(ushort4*)&Al[oi + 4] = lo1;
    }
  }
}

__global__ __launch_bounds__(256) void linear_kernel(const float* __restrict__ h,
                                                     const float* __restrict__ w,
                                                     const float* __restrict__ b,
                                                     float* __restrict__ out) {
  __shared__ float part[16][17];
  int n = blockIdx.x;
  int t = threadIdx.x;
  int c = t & 15, p = t >> 4;
  float sum = 0.f;
#pragma unroll
  for (int q = 0; q < 16; q++) {
    int j = p * 16 + q;
    sum = fmaf(h[(size_t)n * NH + j], w[j * NC + c], sum);
  }
  part[p][c] = sum;
  __syncthreads();
  if (t < 16) {
    float s = 0.f;
#pragma unroll
    for (int p2 = 0; p2 < 16; p2++) s += part[p2][t];
    out[n * NC + t] = s + b[t];
  }
}

extern "C" void kernel_launch(void* const* d_in, const int* in_sizes, int n_in,
                              void* d_out, int out_size, void* d_ws, size_t ws_size,
                              hipStream_t stream) {
  const float* x      = (const float*)d_in[0];
  const int*   src    = (const int*)d_in[1];
  const int*   dst    = (const int*)d_in[2];
  const float* W      = (const float*)d_in[3];
  const float* attn_l = (const float*)d_in[4];
  const float* attn_r = (const float*)d_in[5];
  const float* bias   = (const float*)d_in[6];
  const float* lin_w  = (const float*)d_in[7];
  const float* lin_b  = (const float*)d_in[8];
  float* out = (float*)d_out;

  char* ws = (char*)d_ws;
  size_t off = 0;
  _Float16* zh = (_Float16*)(ws + off); off += (size_t)NET * N_NODES * NH * 2;    // 76.8 MB
  unsigned short* Ah = (unsigned short*)(ws + off); off += (size_t)MPAD * NH * 2; // 25.6 MB
  unsigned short* Al = (unsigned short*)(ws + off); off += (size_t)MPAD * NH * 2; // 25.6 MB
  float* h = (float*)Ah;  // aliases Ah+Al (dead when h is written in the final layer)
  unsigned short* WhT = (unsigned short*)(ws + off); off += (size_t)LAYERS * NET * NH * NH * 2;
  unsigned short* WlT = (unsigned short*)(ws + off); off += (size_t)LAYERS * NET * NH * NH * 2;
  float* el = (float*)(ws + off); off += (size_t)NTOT * HEADS * 4;
  float* er = (float*)(ws + off); off += (size_t)NTOT * HEADS * 4;
  int* rowptr = (int*)(ws + off); off += (size_t)(NTOT + 1) * 4;
  int* colA   = (int*)(ws + off); off += (size_t)NET * NEDGE * 4;
  int* deg    = (int*)(ws + off); off += (size_t)NTOT * 4;
  int* cursor = (int*)(ws + off); off += (size_t)NTOT * 4;
  int* incl   = (int*)(ws + off); off += (size_t)NTOT * 4;
  int* bsum   = (int*)(ws + off); off += 256 * 4;

  // ---- global CSR build over 3N virtual dst nodes ----
  hipMemsetAsync(deg, 0, (size_t)NTOT * 4, stream);
  deg_kernel<<<dim3(NEDGE / 256, NET), 256, 0, stream>>>(dst, deg);
  scan1_kernel<<<SCAN_BLOCKS, 1024, 0, stream>>>(deg, incl, bsum);
  scan2_kernel<<<1, 256, 0, stream>>>(bsum, SCAN_BLOCKS);
  scan3_kernel<<<SCAN_BLOCKS, 1024, 0, stream>>>(incl, bsum, rowptr);
  hipMemcpyAsync(cursor, rowptr, (size_t)NTOT * 4, hipMemcpyDeviceToDevice, stream);
  scatter_kernel<<<dim3(NEDGE / 256, NET), 256, 0, stream>>>(src, dst, cursor, colA);

  // ---- split + transpose all weights once ----
  split_transpose_W<<<(LAYERS * NET * NH * NH + 255) / 256, 256, 0, stream>>>(W, WhT, WlT);

  // ---- layer 0 input split (later layers produce Ah/Al in agg3 epilogue) ----
  split_kernel<<<(N_NODES * NH / 4 + 255) / 256, 256, 0, stream>>>(x, Ah, Al);

  for (int l = 0; l < LAYERS; l++) {
    const float* b0 = bias + (size_t)(l * NET + 0) * NH;
    const float* b1 = bias + (size_t)(l * NET + 1) * NH;
    const float* b2 = bias + (size_t)(l * NET + 2) * NH;

    gemm_split3<<<dim3(MPAD / 64, NET), 256, 0, stream>>>(
        Ah, Al,
        WhT + (size_t)l * NET * NH * NH, WlT + (size_t)l * NET * NH * NH,
        attn_l + (size_t)l * NET * NH, attn_r + (size_t)l * NET * NH,
        zh, el, er, N_NODES);

    agg3_kernel<<<N_NODES / 4, 256, 0, stream>>>(rowptr, colA, el, er, zh, h, Ah, Al,
                                                 b0, b1, b2, l == LAYERS - 1);
  }
  linear_kernel<<<N_NODES, 256, 0, stream>>>(h, lin_w, lin_b, out);
}

// Round 11
// 1296.228 us; speedup vs baseline: 6.5399x; 1.0146x over previous
//
#include <hip/hip_runtime.h>
#include <hip/hip_bf16.h>
#include <math.h>

#define N_NODES 50000
#define NEDGE 800000
#define NET 3
#define LAYERS 3
#define HEADS 4
#define DHEAD 64
#define NH 256
#define NC 16
#define NEG_SLOPE 0.2f
#define MPAD 50048    // 391 * 128
#define NTOT (NET * N_NODES)                 // 150000
#define SCAN_BLOCKS ((NTOT + 1023) / 1024)   // 147
#define GB_PER_T 391                          // MPAD/128 row tiles per etype
#define GEMM_BLOCKS (GB_PER_T * NET)          // 1173
#define SCAT_PER_T 1563                       // ceil(800000/512)
#define SCAT_BLOCKS (SCAT_PER_T * NET)        // 4689

typedef __attribute__((ext_vector_type(8))) short short8;
typedef __attribute__((ext_vector_type(4))) float f32x4;
typedef __attribute__((ext_vector_type(8))) _Float16 half8;

#define GLDS16(gp, lp) \
  __builtin_amdgcn_global_load_lds((const __attribute__((address_space(1))) void*)(gp), \
                                   (__attribute__((address_space(3))) void*)(lp), 16, 0, 0)

__device__ inline unsigned short f2bf(float x) {
  unsigned u = __float_as_uint(x);
  unsigned r = (u + 0x7FFFu + ((u >> 16) & 1u)) >> 16;
  return (unsigned short)r;
}
__device__ inline float bf2f(unsigned short h) { return __uint_as_float(((unsigned)h) << 16); }
__device__ inline float leaky(float v) { return v > 0.f ? v : NEG_SLOPE * v; }

// ================= fused prep: deg || split_x || split_W =================
// blocks [0,9375): deg ; [9375,21875): split x ; [21875,24179): split/transpose W
__global__ __launch_bounds__(256) void prep_kernel(const int* __restrict__ dst,
                                                   int* __restrict__ deg,
                                                   const float* __restrict__ x,
                                                   unsigned short* __restrict__ Ah,
                                                   unsigned short* __restrict__ Al,
                                                   const float* __restrict__ W,
                                                   unsigned short* __restrict__ WhT,
                                                   unsigned short* __restrict__ WlT) {
  int b = blockIdx.x;
  if (b < 9375) {
    int t = b / 3125, r = b % 3125;
    int e = r * 256 + threadIdx.x;                 // 3125*256 == 800000 exact
    atomicAdd(&deg[t * N_NODES + dst[(size_t)t * NEDGE + e]], 1);
  } else if (b < 21875) {
    int i = (b - 9375) * 256 + threadIdx.x;        // 12500*256 == N*NH/4 exact
    float4 v = ((const float4*)x)[i];
    ushort4 h, l;
    h.x = f2bf(v.x); l.x = f2bf(v.x - bf2f(h.x));
    h.y = f2bf(v.y); l.y = f2bf(v.y - bf2f(h.y));
    h.z = f2bf(v.z); l.z = f2bf(v.z - bf2f(h.z));
    h.w = f2bf(v.w); l.w = f2bf(v.w - bf2f(h.w));
    ((ushort4*)Ah)[i] = h;
    ((ushort4*)Al)[i] = l;
  } else {
    int i = (b - 21875) * 256 + threadIdx.x;       // 2304*256 == 9*65536 exact
    int mat = i >> 16, rem = i & 65535;
    int n = rem >> 8, k = rem & 255;
    float v = W[(size_t)mat * 65536 + k * 256 + n];
    unsigned short hi = f2bf(v);
    unsigned short lo = f2bf(v - bf2f(hi));
    WhT[(size_t)mat * 65536 + n * 256 + k] = hi;
    WlT[(size_t)mat * 65536 + n * 256 + k] = lo;
  }
}

// ================= split-bf16 MFMA GEMM, 128x256 tile, 8 waves =================
// wave w: row-group rg=w>>2 (64 rows), head hd=w&3 (64 cols). Fused el/er epilogue.
__device__ __forceinline__ void gemm_dev(int bid,
                                         const unsigned short* __restrict__ Ah,
                                         const unsigned short* __restrict__ Al,
                                         const unsigned short* __restrict__ WhT_l,
                                         const unsigned short* __restrict__ WlT_l,
                                         const float* __restrict__ attn_l_l,
                                         const float* __restrict__ attn_r_l,
                                         _Float16* __restrict__ zh_all,
                                         float* __restrict__ el_all,
                                         float* __restrict__ er_all, int M) {
  __shared__ unsigned short lds[24576];  // Ah 128x32 | Al 128x32 | Bh 256x32 | Bl 256x32
  unsigned short* sAh = lds;
  unsigned short* sAl = lds + 4096;
  unsigned short* sBh = lds + 8192;
  unsigned short* sBl = lds + 16384;

  int t = bid / GB_PER_T, bx = bid % GB_PER_T;
  const unsigned short* BhT = WhT_l + (size_t)t * NH * NH;
  const unsigned short* BlT = WlT_l + (size_t)t * NH * NH;
  const float* al = attn_l_l + (size_t)t * NH;
  const float* ar = attn_r_l + (size_t)t * NH;
  _Float16* zh = zh_all + (size_t)t * N_NODES * NH;
  float* el = el_all + (size_t)t * N_NODES * HEADS;
  float* er = er_all + (size_t)t * N_NODES * HEADS;

  int tid = threadIdx.x;
  int w = tid >> 6, lane = tid & 63;
  int rg = w >> 2, hd = w & 3;
  int r16 = lane & 15, rk = lane >> 4;
  int bm = bx * 128;

  const unsigned short* pAh = Ah + (size_t)(bm + (tid >> 2)) * 256 + (tid & 3) * 8;
  const unsigned short* pAl = Al + (size_t)(bm + (tid >> 2)) * 256 + (tid & 3) * 8;

  f32x4 acc[4][4];
#pragma unroll
  for (int m = 0; m < 4; m++)
#pragma unroll
    for (int n = 0; n < 4; n++) acc[m][n] = (f32x4){0.f, 0.f, 0.f, 0.f};

  char* aBaseH = (char*)sAh + w * 1024;
  char* aBaseL = (char*)sAl + w * 1024;

#pragma unroll
  for (int k0 = 0; k0 < 8; k0++) {
    GLDS16(pAh + k0 * 32, aBaseH);
    GLDS16(pAl + k0 * 32, aBaseL);
#pragma unroll
    for (int i = 0; i < 2; i++) {
      int slot = tid + i * 512;
      size_t go = (size_t)(slot >> 2) * 256 + k0 * 32 + (slot & 3) * 8;
      GLDS16(BhT + go, (char*)sBh + ((size_t)i * 512 + w * 64) * 16);
      GLDS16(BlT + go, (char*)sBl + ((size_t)i * 512 + w * 64) * 16);
    }
    __syncthreads();

    short8 a_h[4], a_l[4], b_h[4], b_l[4];
#pragma unroll
    for (int m = 0; m < 4; m++) {
      int row = rg * 64 + m * 16 + r16;
      a_h[m] = *(const short8*)&sAh[row * 32 + rk * 8];
      a_l[m] = *(const short8*)&sAl[row * 32 + rk * 8];
    }
#pragma unroll
    for (int n = 0; n < 4; n++) {
      int col = hd * 64 + n * 16 + r16;
      b_h[n] = *(const short8*)&sBh[col * 32 + rk * 8];
      b_l[n] = *(const short8*)&sBl[col * 32 + rk * 8];
    }
#pragma unroll
    for (int m = 0; m < 4; m++)
#pragma unroll
      for (int n = 0; n < 4; n++) {
        acc[m][n] = __builtin_amdgcn_mfma_f32_16x16x32_bf16(a_h[m], b_h[n], acc[m][n], 0, 0, 0);
        acc[m][n] = __builtin_amdgcn_mfma_f32_16x16x32_bf16(a_h[m], b_l[n], acc[m][n], 0, 0, 0);
        acc[m][n] = __builtin_amdgcn_mfma_f32_16x16x32_bf16(a_l[m], b_h[n], acc[m][n], 0, 0, 0);
      }
    __syncthreads();
  }

  // C write (fp16)
#pragma unroll
  for (int m = 0; m < 4; m++) {
    int row0 = bm + rg * 64 + m * 16 + rk * 4;
#pragma unroll
    for (int n = 0; n < 4; n++) {
      int col = hd * 64 + n * 16 + r16;
#pragma unroll
      for (int r = 0; r < 4; r++) {
        int row = row0 + r;
        if (row < M) zh[(size_t)row * 256 + col] = (_Float16)acc[m][n][r];
      }
    }
  }

  // fused el/er for head hd
  float alv[4], arv[4];
#pragma unroll
  for (int n = 0; n < 4; n++) {
    alv[n] = al[hd * 64 + n * 16 + r16];
    arv[n] = ar[hd * 64 + n * 16 + r16];
  }
#pragma unroll
  for (int m = 0; m < 4; m++) {
#pragma unroll
    for (int r = 0; r < 4; r++) {
      float pl = 0.f, pr = 0.f;
#pragma unroll
      for (int n = 0; n < 4; n++) {
        float zv = acc[m][n][r];
        pl = fmaf(zv, alv[n], pl);
        pr = fmaf(zv, arv[n], pr);
      }
      pl += __shfl_xor(pl, 1, 64); pl += __shfl_xor(pl, 2, 64);
      pl += __shfl_xor(pl, 4, 64); pl += __shfl_xor(pl, 8, 64);
      pr += __shfl_xor(pr, 1, 64); pr += __shfl_xor(pr, 2, 64);
      pr += __shfl_xor(pr, 4, 64); pr += __shfl_xor(pr, 8, 64);
      int row = bm + rg * 64 + m * 16 + rk * 4 + r;
      if (r16 == 0 && row < M) {
        el[row * HEADS + hd] = pl;
        er[row * HEADS + hd] = pr;
      }
    }
  }
}

// fused: scatter (blocks [0,4689)) || layer-0 GEMM (blocks [4689,5862))
__global__ __launch_bounds__(512) void gemm0_scatter_kernel(
    const unsigned short* __restrict__ Ah, const unsigned short* __restrict__ Al,
    const unsigned short* __restrict__ WhT_l, const unsigned short* __restrict__ WlT_l,
    const float* __restrict__ attn_l_l, const float* __restrict__ attn_r_l,
    _Float16* __restrict__ zh_all, float* __restrict__ el_all, float* __restrict__ er_all,
    int M,
    const int* __restrict__ src, const int* __restrict__ dst,
    int* __restrict__ cursor, int* __restrict__ col) {
  if (blockIdx.x < SCAT_BLOCKS) {
    int b = blockIdx.x;
    int t = b / SCAT_PER_T, r = b % SCAT_PER_T;
    int e = r * 512 + (int)threadIdx.x;
    if (e < NEDGE) {
      int d = dst[(size_t)t * NEDGE + e];
      int pos = atomicAdd(&cursor[t * N_NODES + d], 1);
      col[pos] = src[(size_t)t * NEDGE + e] + t * N_NODES;
    }
  } else {
    gemm_dev(blockIdx.x - SCAT_BLOCKS, Ah, Al, WhT_l, WlT_l, attn_l_l, attn_r_l,
             zh_all, el_all, er_all, M);
  }
}

__global__ __launch_bounds__(512) void gemm_split3(
    const unsigned short* __restrict__ Ah, const unsigned short* __restrict__ Al,
    const unsigned short* __restrict__ WhT_l, const unsigned short* __restrict__ WlT_l,
    const float* __restrict__ attn_l_l, const float* __restrict__ attn_r_l,
    _Float16* __restrict__ zh_all, float* __restrict__ el_all, float* __restrict__ er_all,
    int M) {
  gemm_dev(blockIdx.x, Ah, Al, WhT_l, WlT_l, attn_l_l, attn_r_l, zh_all, el_all, er_all, M);
}

// ================= hierarchical scan =================
__global__ __launch_bounds__(1024) void scan1_kernel(const int* __restrict__ deg,
                                                     int* __restrict__ incl,
                                                     int* __restrict__ bsum) {
  __shared__ int wsum[16];
  int tid = threadIdx.x;
  int gid = blockIdx.x * 1024 + tid;
  int lane = tid & 63, wv = tid >> 6;
  int v = (gid < NTOT) ? deg[gid] : 0;
  int x = v;
#pragma unroll
  for (int off = 1; off < 64; off <<= 1) {
    int y = __shfl_up(x, off, 64);
    if (lane >= off) x += y;
  }
  if (lane == 63) wsum[wv] = x;
  __syncthreads();
  if (wv == 0 && lane < 16) {
    int s = wsum[lane];
#pragma unroll
    for (int off = 1; off < 16; off <<= 1) {
      int y = __shfl_up(s, off, 16);
      if (lane >= off) s += y;
    }
    wsum[lane] = s;
  }
  __syncthreads();
  int waveoff = (wv > 0) ? wsum[wv - 1] : 0;
  int inclv = x + waveoff;
  if (gid < NTOT) incl[gid] = inclv;
  if (tid == 1023) bsum[blockIdx.x] = inclv;
}

__global__ __launch_bounds__(256) void scan2_kernel(int* __restrict__ bsum, int nb) {
  __shared__ int wsum[4];
  int tid = threadIdx.x;
  int lane = tid & 63, wv = tid >> 6;
  int v = (tid < nb) ? bsum[tid] : 0;
  int x = v;
#pragma unroll
  for (int off = 1; off < 64; off <<= 1) {
    int y = __shfl_up(x, off, 64);
    if (lane >= off) x += y;
  }
  if (lane == 63) wsum[wv] = x;
  __syncthreads();
  if (wv == 0 && lane < 4) {
    int s = wsum[lane];
#pragma unroll
    for (int off = 1; off < 4; off <<= 1) {
      int y = __shfl_up(s, off, 4);
      if (lane >= off) s += y;
    }
    wsum[lane] = s;
  }
  __syncthreads();
  int waveoff = (wv > 0) ? wsum[wv - 1] : 0;
  if (tid < nb) bsum[tid] = x + waveoff - v;  // exclusive
}

__global__ __launch_bounds__(1024) void scan3_kernel(const int* __restrict__ incl,
                                                     const int* __restrict__ bsum,
                                                     int* __restrict__ rowptr) {
  int tid = threadIdx.x;
  int gid = blockIdx.x * 1024 + tid;
  if (gid < NTOT) rowptr[gid + 1] = incl[gid] + bsum[blockIdx.x];
  if (gid == 0) rowptr[0] = 0;
}

// ================= fused 3-etype softmax + aggregation + split epilogue =================
__global__ __launch_bounds__(256) void agg3_kernel(const int* __restrict__ rowptr,
                                                   const int* __restrict__ col,
                                                   const float* __restrict__ el,
                                                   const float* __restrict__ er,
                                                   const _Float16* __restrict__ zh,
                                                   float* __restrict__ hout,
                                                   unsigned short* __restrict__ Ah,
                                                   unsigned short* __restrict__ Al,
                                                   const float* __restrict__ b0,
                                                   const float* __restrict__ b1,
                                                   const float* __restrict__ b2,
                                                   int final_layer) {
  __shared__ float s_alpha[4][128][4];
  __shared__ int s_col[4][128];

  int wv = threadIdx.x >> 6, lane = threadIdx.x & 63;
  int n = blockIdx.x * 4 + wv;
  int kk = lane & 15, hh = lane >> 4;
  int which = lane >> 5, lj = lane & 31, fh = lj >> 3;

  float v0 = 0.f, v1 = 0.f, v2 = 0.f, v3 = 0.f;
  float v4 = 0.f, v5 = 0.f, v6 = 0.f, v7 = 0.f;

  for (int t = 0; t < NET; t++) {
    int gn = t * N_NODES + n;
    int rs = rowptr[gn];
    int deg = rowptr[gn + 1] - rs;
    float erh = er[(size_t)gn * HEADS + hh];

    float sm = 0.f;
    float a0 = 0.f, a1 = 0.f, a2 = 0.f, a3 = 0.f;
    float a4 = 0.f, a5 = 0.f, a6 = 0.f, a7 = 0.f;

    for (int s0 = 0; s0 < deg; s0 += 128) {
      int segN = min(128, deg - s0);
      // phase A: 16 edges x 4 heads per iteration
      for (int c0 = 0; c0 < segN; c0 += 16) {
        if (c0 + kk < segN) {
          int row = col[rs + s0 + c0 + kk];
          float a = __expf(leaky(el[(size_t)row * HEADS + hh] + erh));
          sm += a;
          s_alpha[wv][c0 + kk][hh] = a;
          if (hh == 0) s_col[wv][c0 + kk] = row;
        }
      }
      // phase B: x2 unrolled (4 z rows in flight per wave)
      int k = which;
      for (; k + 2 < segN; k += 4) {
        float aa = s_alpha[wv][k][fh];     int ra = s_col[wv][k];
        float ab = s_alpha[wv][k + 2][fh]; int rb = s_col[wv][k + 2];
        half8 va = *(const half8*)&zh[(size_t)ra * NH + lj * 8];
        half8 vb = *(const half8*)&zh[(size_t)rb * NH + lj * 8];
        a0 = fmaf(aa, (float)va[0], a0); a1 = fmaf(aa, (float)va[1], a1);
        a2 = fmaf(aa, (float)va[2], a2); a3 = fmaf(aa, (float)va[3], a3);
        a4 = fmaf(aa, (float)va[4], a4); a5 = fmaf(aa, (float)va[5], a5);
        a6 = fmaf(aa, (float)va[6], a6); a7 = fmaf(aa, (float)va[7], a7);
        a0 = fmaf(ab, (float)vb[0], a0); a1 = fmaf(ab, (float)vb[1], a1);
        a2 = fmaf(ab, (float)vb[2], a2); a3 = fmaf(ab, (float)vb[3], a3);
        a4 = fmaf(ab, (float)vb[4], a4); a5 = fmaf(ab, (float)vb[5], a5);
        a6 = fmaf(ab, (float)vb[6], a6); a7 = fmaf(ab, (float)vb[7], a7);
      }
      for (; k < segN; k += 2) {
        float aa = s_alpha[wv][k][fh];
        int ra = s_col[wv][k];
        half8 va = *(const half8*)&zh[(size_t)ra * NH + lj * 8];
        a0 = fmaf(aa, (float)va[0], a0); a1 = fmaf(aa, (float)va[1], a1);
        a2 = fmaf(aa, (float)va[2], a2); a3 = fmaf(aa, (float)va[3], a3);
        a4 = fmaf(aa, (float)va[4], a4); a5 = fmaf(aa, (float)va[5], a5);
        a6 = fmaf(aa, (float)va[6], a6); a7 = fmaf(aa, (float)va[7], a7);
      }
    }

    sm += __shfl_xor(sm, 1, 64);
    sm += __shfl_xor(sm, 2, 64);
    sm += __shfl_xor(sm, 4, 64);
    sm += __shfl_xor(sm, 8, 64);
    float inv = (deg > 0) ? 1.f / sm : 0.f;
    float invb = __shfl(inv, fh * 16, 64);

    a0 += __shfl_xor(a0, 32, 64); a1 += __shfl_xor(a1, 32, 64);
    a2 += __shfl_xor(a2, 32, 64); a3 += __shfl_xor(a3, 32, 64);
    a4 += __shfl_xor(a4, 32, 64); a5 += __shfl_xor(a5, 32, 64);
    a6 += __shfl_xor(a6, 32, 64); a7 += __shfl_xor(a7, 32, 64);

    v0 = fmaf(a0, invb, v0); v1 = fmaf(a1, invb, v1);
    v2 = fmaf(a2, invb, v2); v3 = fmaf(a3, invb, v3);
    v4 = fmaf(a4, invb, v4); v5 = fmaf(a5, invb, v5);
    v6 = fmaf(a6, invb, v6); v7 = fmaf(a7, invb, v7);
  }

  if (lane < 32) {
    int f0 = lj * 8;
    float vo[8] = {v0, v1, v2, v3, v4, v5, v6, v7};
#pragma unroll
    for (int i = 0; i < 8; i++) vo[i] += b0[f0 + i] + b1[f0 + i] + b2[f0 + i];
    if (final_layer) {
      size_t oi = (size_t)n * NH + f0;
      float4 o0 = {vo[0], vo[1], vo[2], vo[3]};
      float4 o1 = {vo[4], vo[5], vo[6], vo[7]};
      *(float4*)&hout[oi] = o0;
      *(float4*)&hout[oi + 4] = o1;
    } else {
      ushort4 hi0, hi1, lo0, lo1;
#pragma unroll
      for (int i = 0; i < 8; i++) vo[i] = fmaxf(vo[i], 0.f);  // relu
      hi0.x = f2bf(vo[0]); lo0.x = f2bf(vo[0] - bf2f(hi0.x));
      hi0.y = f2bf(vo[1]); lo0.y = f2bf(vo[1] - bf2f(hi0.y));
      hi0.z = f2bf(vo[2]); lo0.z = f2bf(vo[2] - bf2f(hi0.z));
      hi0.w = f2bf(vo[3]); lo0.w = f2bf(vo[3] - bf2f(hi0.w));
      hi1.x = f2bf(vo[4]); lo1.x = f2bf(vo[4] - bf2f(hi1.x));
      hi1.y = f2bf(vo[5]); lo1.y = f2bf(vo[5] - bf2f(hi1.y));
      hi1.z = f2bf(vo[6]); lo1.z = f2bf(vo[6] - bf2f(hi1.z));
      hi1.w = f2bf(vo[7]); lo1.w = f2bf(vo[7] - bf2f(hi1.w));
      size_t oi = (size_t)n * NH + f0;
      *(ushort4*)&Ah[oi] = hi0;
      *(ushort4*)&Ah[oi + 4] = hi1;
      *(ushort4*)&Al[oi] = lo0;
      *(ushort4*)&Al[oi + 4] = lo1;
    }
  }
}

__global__ __launch_bounds__(256) void linear_kernel(const float* __restrict__ h,
                                                     const float* __restrict__ w,
                                                     const float* __restrict__ b,
                                                     float* __restrict__ out) {
  __shared__ float part[16][17];
  int n = blockIdx.x;
  int t = threadIdx.x;
  int c = t & 15, p = t >> 4;
  float sum = 0.f;
#pragma unroll
  for (int q = 0; q < 16; q++) {
    int j = p * 16 + q;
    sum = fmaf(h[(size_t)n * NH + j], w[j * NC + c], sum);
  }
  part[p][c] = sum;
  __syncthreads();
  if (t < 16) {
    float s = 0.f;
#pragma unroll
    for (int p2 = 0; p2 < 16; p2++) s += part[p2][t];
    out[n * NC + t] = s + b[t];
  }
}

extern "C" void kernel_launch(void* const* d_in, const int* in_sizes, int n_in,
                              void* d_out, int out_size, void* d_ws, size_t ws_size,
                              hipStream_t stream) {
  const float* x      = (const float*)d_in[0];
  const int*   src    = (const int*)d_in[1];
  const int*   dst    = (const int*)d_in[2];
  const float* W      = (const float*)d_in[3];
  const float* attn_l = (const float*)d_in[4];
  const float* attn_r = (const float*)d_in[5];
  const float* bias   = (const float*)d_in[6];
  const float* lin_w  = (const float*)d_in[7];
  const float* lin_b  = (const float*)d_in[8];
  float* out = (float*)d_out;

  char* ws = (char*)d_ws;
  size_t off = 0;
  _Float16* zh = (_Float16*)(ws + off); off += (size_t)NET * N_NODES * NH * 2;    // 76.8 MB
  unsigned short* Ah = (unsigned short*)(ws + off); off += (size_t)MPAD * NH * 2; // 25.6 MB
  unsigned short* Al = (unsigned short*)(ws + off); off += (size_t)MPAD * NH * 2; // 25.6 MB
  float* h = (float*)Ah;  // aliases Ah+Al (dead when h is written in the final layer)
  unsigned short* WhT = (unsigned short*)(ws + off); off += (size_t)LAYERS * NET * NH * NH * 2;
  unsigned short* WlT = (unsigned short*)(ws + off); off += (size_t)LAYERS * NET * NH * NH * 2;
  float* el = (float*)(ws + off); off += (size_t)NTOT * HEADS * 4;
  float* er = (float*)(ws + off); off += (size_t)NTOT * HEADS * 4;
  int* rowptr = (int*)(ws + off); off += (size_t)(NTOT + 1) * 4;
  int* colA   = (int*)(ws + off); off += (size_t)NET * NEDGE * 4;
  int* deg    = (int*)(ws + off); off += (size_t)NTOT * 4;
  int* cursor = (int*)(ws + off); off += (size_t)NTOT * 4;
  int* incl   = (int*)(ws + off); off += (size_t)NTOT * 4;
  int* bsum   = (int*)(ws + off); off += 256 * 4;

  // ---- prep: deg || split_x || split_W ----
  hipMemsetAsync(deg, 0, (size_t)NTOT * 4, stream);
  prep_kernel<<<24179, 256, 0, stream>>>(dst, deg, x, Ah, Al, W, WhT, WlT);

  // ---- scan -> rowptr ; cursor = rowptr ----
  scan1_kernel<<<SCAN_BLOCKS, 1024, 0, stream>>>(deg, incl, bsum);
  scan2_kernel<<<1, 256, 0, stream>>>(bsum, SCAN_BLOCKS);
  scan3_kernel<<<SCAN_BLOCKS, 1024, 0, stream>>>(incl, bsum, rowptr);
  hipMemcpyAsync(cursor, rowptr, (size_t)NTOT * 4, hipMemcpyDeviceToDevice, stream);

  // ---- layer 0: scatter || gemm fused ----
  gemm0_scatter_kernel<<<SCAT_BLOCKS + GEMM_BLOCKS, 512, 0, stream>>>(
      Ah, Al, WhT, WlT, attn_l, attn_r, zh, el, er, N_NODES, src, dst, cursor, colA);

  for (int l = 0; l < LAYERS; l++) {
    const float* b0 = bias + (size_t)(l * NET + 0) * NH;
    const float* b1 = bias + (size_t)(l * NET + 1) * NH;
    const float* b2 = bias + (size_t)(l * NET + 2) * NH;

    if (l > 0) {
      gemm_split3<<<GEMM_BLOCKS, 512, 0, stream>>>(
          Ah, Al,
          WhT + (size_t)l * NET * NH * NH, WlT + (size_t)l * NET * NH * NH,
          attn_l + (size_t)l * NET * NH, attn_r + (size_t)l * NET * NH,
          zh, el, er, N_NODES);
    }
    agg3_kernel<<<N_NODES / 4, 256, 0, stream>>>(rowptr, colA, el, er, zh, h, Ah, Al,
                                                 b0, b1, b2, l == LAYERS - 1);
  }
  linear_kernel<<<N_NODES, 256, 0, stream>>>(h, lin_w, lin_b, out);
}